// Round 12
// baseline (427.342 us; speedup 1.0000x reference)
//
#include <hip/hip_runtime.h>
#include <hip/hip_fp16.h>

#define N_NODES 40000
#define N_EDGES 400000
#define N_GRAPHS 64
#define D1 256      // heads*hid for conv1
#define HIDC 64
#define NHEADS 4
#define EDIM 18
#define EPAD 32     // staged row = one aligned 128B line, fully written by 1 thread
                    // 0..17 ea | 18,19 x[src] | 20 src | 21 dst | 22..31 zero
#define OUTF 3
#define APAD 264    // LDS row stride in halfs for nl2 (256 + 8 pad)
#define NROWS2 32   // rows per MFMA block (1250 blocks -> occupancy; R7 win)
#define AP1 104     // LDS row stride in halfs for fin1 (96 + 8 pad)

typedef _Float16 f16x8 __attribute__((ext_vector_type(8)));
typedef float f32x4 __attribute__((ext_vector_type(4)));

// ---------------- prep: pack conv2 weights + conv1 cbuf + conv1 finalize
// MFMA weights Btf (96x272 block-diag + beta column) + beta scalars ---------
__global__ void prep_w(const float* __restrict__ Wq, const float* __restrict__ bq,
                       const float* __restrict__ Wk, const float* __restrict__ bk,
                       const float* __restrict__ Wv, const float* __restrict__ bv,
                       const float* __restrict__ Ws, const float* __restrict__ bs,
                       const float* __restrict__ We2,
                       const float* __restrict__ Wq1, const float* __restrict__ bq1,
                       const float* __restrict__ Wk1, const float* __restrict__ bk1,
                       const float* __restrict__ We1,
                       const float* __restrict__ Wv1, const float* __restrict__ bv1,
                       const float* __restrict__ Ws1, const float* __restrict__ bs1,
                       const float* __restrict__ Wb1,
                       __half* __restrict__ Bt, float* __restrict__ bias,
                       float* __restrict__ cbuf, __half* __restrict__ Btf) {
    int c = blockIdx.x, k = threadIdx.x;
    if (c < 256) {
        int m = c >> 6, d = c & 63;
        const float* W = (m == 0) ? Wq : (m == 1) ? Wk : (m == 2) ? Wv : Ws;
        Bt[c * 256 + k] = __float2half(W[k * 64 + d]);
        if (k == 0) {
            const float* b = (m == 0) ? bq : (m == 1) ? bk : (m == 2) ? bv : bs;
            bias[c] = b[d];
        }
    } else if (c < 288) {
        int j = c - 256;
        float s = 0.f;
        if (j < EDIM)
            for (int cc = 0; cc < 64; ++cc) s += Wq[k * 64 + cc] * We2[j * 64 + cc];
        Bt[c * 256 + k] = __float2half(s);
        if (k == 0) {
            float b = 0.f;
            if (j < EDIM)
                for (int cc = 0; cc < 64; ++cc) b += bq[cc] * We2[j * 64 + cc];
            bias[c] = b;
        }
    } else if (c == 288) {
        int t = k;
        if (t < 36) {
            int h = t / 9, r = t % 9, a = r / 3, b = r % 3;
            const float* A = (a == 0) ? Wq1 : (a == 1) ? Wq1 + D1 : bq1;
            const float* B = (b == 0) ? Wk1 : (b == 1) ? Wk1 + D1 : bk1;
            float s = 0.f;
            for (int cc = 0; cc < 64; ++cc) s += A[h * 64 + cc] * B[h * 64 + cc];
            cbuf[h * 63 + a * 3 + b] = s;
        } else if (t < 252) {
            int i = t - 36;
            int h = i / 54, rr = (i % 54) / 18, j = i % 18;
            const float* A = (rr == 0) ? Wq1 : (rr == 1) ? Wq1 + D1 : bq1;
            float s = 0.f;
            for (int cc = 0; cc < 64; ++cc) s += A[h * 64 + cc] * We1[j * D1 + h * 64 + cc];
            cbuf[h * 63 + 9 + rr * 18 + j] = s;
        }
    } else if (c < 561) {
        // Btf[c2][k]: conv1 finalize weights, K=96 (4 heads x 24), N=272.
        int c2 = c - 289;
        if (k < 96) {
            int hk = k / 24, j = k % 24;
            float val = 0.f;
            if (c2 < 256) {
                int hh = c2 >> 6;
                if (hk == hh && j < 21) {
                    val = (j == 0) ? Wv1[c2] : (j == 1) ? Wv1[D1 + c2] :
                          (j == 2) ? bv1[c2] : We1[(j - 3) * D1 + c2];
                }
            } else if (c2 == 256) {
                if (j < 21) {
                    float s = 0.f;
                    for (int d = 0; d < 64; ++d) {
                        int col = hk * 64 + d;
                        float wr = (j == 0) ? Wv1[col] : (j == 1) ? Wv1[D1 + col] :
                                   (j == 2) ? bv1[col] : We1[(j - 3) * D1 + col];
                        s += wr * (Wb1[col] + Wb1[2 * D1 + col]);
                    }
                    val = s;
                }
            }
            Btf[c2 * 96 + k] = __float2half(val);
        }
    } else {
        // beta xr-part scalars: s0,s1,s2 -> bias[288..290]
        if (k < 3) {
            float s = 0.f;
            for (int d = 0; d < D1; ++d) {
                float u = Wb1[D1 + d] - Wb1[2 * D1 + d];
                float w = (k == 0) ? Ws1[d] : (k == 1) ? Ws1[D1 + d] : bs1[d];
                s += w * u;
            }
            bias[288 + k] = s;
        }
    }
}

// ---------------- init (zero fill, merged) ----------------
__global__ void initA(float* __restrict__ acc1, float* __restrict__ acc2,
                      float* __restrict__ out2, int* __restrict__ deg,
                      float* __restrict__ pooled,
                      int* __restrict__ gs, int* __restrict__ ge) {
    int t = blockIdx.x * 256 + threadIdx.x;      // N*84 threads exact
    acc1[t] = 0.f;
    if (t < N_NODES * 64) out2[t] = 0.f;
    if (t < N_NODES * 20) acc2[t] = 0.f;
    if (t < N_NODES) deg[t] = 0;
    if (t < N_GRAPHS * HIDC) pooled[t] = 0.f;
    if (t < N_GRAPHS) { gs[t] = 0; ge[t] = 0; }
}

// ---------------- CSR hist + graph bounds (merged) ----------------
__global__ void hist_kernel(const int* __restrict__ ei, int* __restrict__ deg,
                            const int* __restrict__ batch, int* __restrict__ gs,
                            int* __restrict__ ge) {
    int e = blockIdx.x * 256 + threadIdx.x;
    if (e < N_EDGES) atomicAdd(&deg[ei[N_EDGES + e]], 1);
    int n = e;
    if (n < N_NODES) {
        int b = batch[n];
        if (n == 0) gs[b] = 0;
        else { int pb = batch[n - 1]; if (pb != b) { ge[pb] = n; gs[b] = n; } }
        if (n == N_NODES - 1) ge[b] = N_NODES;
    }
}

// ---------------- 3-kernel coalesced scan -> cursor ----------------
__global__ void scanA(const int* __restrict__ deg, int* __restrict__ bsum) {
    __shared__ int s[256];
    int b = blockIdx.x, t = threadIdx.x;
    s[t] = (t < 160) ? deg[b * 160 + t] : 0;
    __syncthreads();
    for (int off = 128; off; off >>= 1) {
        if (t < off) s[t] += s[t + off];
        __syncthreads();
    }
    if (t == 0) bsum[b] = s[0];
}

__global__ void scanB(const int* __restrict__ bsum, int* __restrict__ boff) {
    __shared__ int s[256];
    int t = threadIdx.x;
    int v = (t < 250) ? bsum[t] : 0;
    s[t] = v;
    __syncthreads();
    for (int off = 1; off < 256; off <<= 1) {
        int add = (t >= off) ? s[t - off] : 0;
        __syncthreads();
        s[t] += add;
        __syncthreads();
    }
    if (t < 250) boff[t] = s[t] - v;             // exclusive
}

__global__ void scanC(const int* __restrict__ deg, const int* __restrict__ boff,
                      int* __restrict__ cursor) {
    __shared__ int s[256];
    int b = blockIdx.x, t = threadIdx.x;
    int v = (t < 160) ? deg[b * 160 + t] : 0;
    s[t] = v;
    __syncthreads();
    for (int off = 1; off < 256; off <<= 1) {
        int add = (t >= off) ? s[t - off] : 0;
        __syncthreads();
        s[t] += add;
        __syncthreads();
    }
    if (t < 160) cursor[b * 160 + t] = boff[b] + s[t] - v;
}

// ---------------- fused perm + scatter staging (e-order, coalesced reads) ---
// 2 edges/thread: both atomics issued up front (independent latency chains),
// rows processed sequentially to bound VGPR. Lean body -- no logit math
// (R2's spill failure mode avoided).
__global__ void scatterE(const int* __restrict__ ei, const float* __restrict__ ea,
                         const float* __restrict__ x, int* __restrict__ cursor,
                         float* __restrict__ ea_s) {
    const int HALF = N_EDGES / 2;
    int e0 = blockIdx.x * 256 + threadIdx.x;
    if (e0 >= HALF) return;
    int eA = e0, eB = e0 + HALF;
    int srcA = ei[eA], dstA = ei[N_EDGES + eA];
    int srcB = ei[eB], dstB = ei[N_EDGES + eB];
    int pA = atomicAdd(&cursor[dstA], 1);
    int pB = atomicAdd(&cursor[dstB], 1);
    #pragma unroll
    for (int half = 0; half < 2; ++half) {
        int e   = half ? eB : eA;
        int src = half ? srcB : srcA;
        int dst = half ? dstB : dstA;
        int p   = half ? pB : pA;
        const float2* sr = (const float2*)(ea + (size_t)e * EDIM);   // 8B aligned
        float2 s0 = sr[0], s1 = sr[1], s2 = sr[2], s3 = sr[3], s4 = sr[4],
               s5 = sr[5], s6 = sr[6], s7 = sr[7], s8 = sr[8];
        float2 xv = *(const float2*)(x + (size_t)src * 2);           // L2-hit
        float4* drow = (float4*)(ea_s + (size_t)p * EPAD);           // 128B line
        drow[0] = make_float4(s0.x, s0.y, s1.x, s1.y);
        drow[1] = make_float4(s2.x, s2.y, s3.x, s3.y);
        drow[2] = make_float4(s4.x, s4.y, s5.x, s5.y);
        drow[3] = make_float4(s6.x, s6.y, s7.x, s7.y);
        drow[4] = make_float4(s8.x, s8.y, xv.x, xv.y);
        drow[5] = make_float4(__int_as_float(src), __int_as_float(dst), 0.f, 0.f);
        drow[6] = make_float4(0.f, 0.f, 0.f, 0.f);
        drow[7] = make_float4(0.f, 0.f, 0.f, 0.f);
    }
}

// ---------------- conv1 logits, p-order (coalesced row reads) ---------------
__global__ void logits1(const float* __restrict__ ea_s, const float* __restrict__ x,
                        const float* __restrict__ cbuf, float* __restrict__ w1) {
    __shared__ float cb[252];
    int t = threadIdx.x;
    if (t < 252) cb[t] = cbuf[t];
    __syncthreads();
    int p = blockIdx.x * 256 + t;
    if (p >= N_EDGES) return;
    const float4* row = (const float4*)(ea_s + (size_t)p * EPAD);
    float4 r0 = row[0], r1 = row[1], r2 = row[2], r3 = row[3], r4 = row[4], r5 = row[5];
    float s[EDIM];
    s[0]=r0.x; s[1]=r0.y; s[2]=r0.z; s[3]=r0.w;
    s[4]=r1.x; s[5]=r1.y; s[6]=r1.z; s[7]=r1.w;
    s[8]=r2.x; s[9]=r2.y; s[10]=r2.z; s[11]=r2.w;
    s[12]=r3.x; s[13]=r3.y; s[14]=r3.z; s[15]=r3.w;
    s[16]=r4.x; s[17]=r4.y;
    float xs0 = r4.z, xs1 = r4.w;
    int dst = __float_as_int(r5.y);
    float2 xd = *(const float2*)(x + (size_t)dst * 2);           // L2-hit
    float w[NHEADS];
    #pragma unroll
    for (int h = 0; h < NHEADS; ++h) {
        const float* c = cb + h * 63;
        float alpha = 0.f;
        #pragma unroll
        for (int a = 0; a < 3; ++a) {
            float tv = c[a * 3] * xs0 + c[a * 3 + 1] * xs1 + c[a * 3 + 2];
            const float* cc = c + 9 + a * 18;
            #pragma unroll
            for (int j = 0; j < EDIM; ++j) tv += cc[j] * s[j];
            alpha += tv * ((a == 0) ? xd.x : (a == 1) ? xd.y : 1.f);
        }
        w[h] = __expf(alpha * 0.125f);
    }
    *(float4*)(w1 + (size_t)p * 4) = make_float4(w[0], w[1], w[2], w[3]);
}

// ---------------- conv1: 16-edge strip, pure segmented acc += w*v -----------
__global__ void strip1f(const float* __restrict__ ea_s, const float* __restrict__ w1,
                        float* __restrict__ acc1) {
    int t = threadIdx.x;
    int strip = blockIdx.x * 2 + (t >> 7);       // 2 strips per 256-block
    int l = t & 127;
    int h = l >> 5, comp = l & 31;
    bool active = comp < 21;
    int voff = (comp == 0) ? 18 : (comp == 1) ? 19 : (comp >= 3 ? comp - 3 : 0);
    bool isone = (comp == 2);
    int cidx = h * 21 + comp;                    // valid when active
    int p0 = strip * 16;
    int dsts[16]; float v[16]; float w[16];
    #pragma unroll
    for (int j = 0; j < 16; ++j)
        dsts[j] = __float_as_int(ea_s[(size_t)(p0 + j) * EPAD + 21]);
    #pragma unroll
    for (int j = 0; j < 16; ++j) w[j] = w1[(size_t)(p0 + j) * 4 + h];
    #pragma unroll
    for (int j = 0; j < 16; ++j)
        v[j] = active ? (isone ? 1.f : ea_s[(size_t)(p0 + j) * EPAD + voff]) : 0.f;
    float acc = 0.f;
    int prev = dsts[0];
    #pragma unroll
    for (int j = 0; j < 16; ++j) {
        if (dsts[j] != prev) {                   // wave-uniform branch
            if (active) atomicAdd(&acc1[(size_t)prev * 84 + cidx], acc);
            acc = 0.f; prev = dsts[j];
        }
        acc += w[j] * v[j];
    }
    if (active) atomicAdd(&acc1[(size_t)prev * 84 + cidx], acc);
}

// ---------------- conv1 finalize stage A: a_sc = acc1/l as half, K=96 -------
__global__ void scale1(const float* __restrict__ acc1, __half* __restrict__ ah) {
    int tg = blockIdx.x * 256 + threadIdx.x;     // N*96 threads exact
    int node = tg / 96, k = tg % 96;
    int h = k / 24, j = k % 24;
    float val = 0.f;
    if (j < 21) {
        const float* a = acc1 + (size_t)node * 84 + h * 21;
        float l = a[2];
        float inv = 1.f / (l + 1e-16f);
        val = (j == 2) ? l * inv : a[j] * inv;
    }
    ah[tg] = __float2half(val);
}

// ---------------- conv1 finalize stage B: MFMA matvec + beta + relu ---------
__global__ __launch_bounds__(256) void fin1_mfma(
        const __half* __restrict__ ah, const __half* __restrict__ Btf,
        const float* __restrict__ x, const float* __restrict__ bias,
        const float* __restrict__ Wskip, const float* __restrict__ bskip,
        __half* __restrict__ h1f) {
    __shared__ _Float16 As[32 * AP1];
    __shared__ float betaL[32];
    int t = threadIdx.x;
    int row0 = blockIdx.x * 32;
    const float4* gsrc = (const float4*)(ah + (size_t)row0 * 96);
    #pragma unroll
    for (int i = 0; i < 2; ++i) {
        int li = i * 256 + t;                    // 384 chunks of 8 halfs
        if (li < 384) {
            int r = li / 12, c8 = li % 12;
            *(float4*)(As + r * AP1 + c8 * 8) = gsrc[li];
        }
    }
    __syncthreads();
    int wave = t >> 6, lane = t & 63, quad = lane >> 4, mm = lane & 15;
    const _Float16* Bp = (const _Float16*)Btf;
    int ct0 = (wave == 0) ? 16 : wave;
    f32x4 st[2];
    {
        int c0 = ct0 * 16 + mm;
        const _Float16* b0 = Bp + (size_t)c0 * 96 + quad * 8;
        f16x8 b0v = *(const f16x8*)(b0);
        f16x8 b1v = *(const f16x8*)(b0 + 32);
        f16x8 b2v = *(const f16x8*)(b0 + 64);
        #pragma unroll
        for (int rt = 0; rt < 2; ++rt) {
            const _Float16* ar = As + (rt * 16 + mm) * AP1 + quad * 8;
            f32x4 acc = {0.f, 0.f, 0.f, 0.f};
            acc = __builtin_amdgcn_mfma_f32_16x16x32_f16(*(const f16x8*)(ar),      b0v, acc, 0, 0, 0);
            acc = __builtin_amdgcn_mfma_f32_16x16x32_f16(*(const f16x8*)(ar + 32), b1v, acc, 0, 0, 0);
            acc = __builtin_amdgcn_mfma_f32_16x16x32_f16(*(const f16x8*)(ar + 64), b2v, acc, 0, 0, 0);
            st[rt] = acc;
        }
        if (wave == 0 && mm == 0) {              // col 256 lanes -> beta partials
            #pragma unroll
            for (int rt = 0; rt < 2; ++rt)
                #pragma unroll
                for (int r = 0; r < 4; ++r)
                    betaL[rt * 16 + quad * 4 + r] = st[rt][r];
        }
    }
    __syncthreads();
    if (t < 32) {
        int nd = row0 + t;
        float x0 = x[nd * 2], x1 = x[nd * 2 + 1];
        float lg = betaL[t] + x0 * bias[288] + x1 * bias[289] + bias[290];
        betaL[t] = 1.f / (1.f + __expf(-lg));
    }
    __syncthreads();
    if (wave != 0) {
        int c0 = ct0 * 16 + mm;
        float w0 = Wskip[c0], w1s = Wskip[D1 + c0], bsv = bskip[c0];
        #pragma unroll
        for (int rt = 0; rt < 2; ++rt)
            #pragma unroll
            for (int r = 0; r < 4; ++r) {
                int lr = rt * 16 + quad * 4 + r, gr = row0 + lr;
                float beta = betaL[lr];
                float x0 = x[gr * 2], x1 = x[gr * 2 + 1];
                float xr = x0 * w0 + x1 * w1s + bsv;
                h1f[(size_t)gr * D1 + c0] =
                    __float2half(fmaxf(beta * xr + (1.f - beta) * st[rt][r], 0.f));
            }
    }
    int nit = (wave == 0) ? 5 : 4;
    for (int it = 1; it < nit; ++it) {
        int ct = (wave == 0) ? (it - 1) * 4 : wave + it * 4;
        int c0 = ct * 16 + mm;
        const _Float16* b0 = Bp + (size_t)c0 * 96 + quad * 8;
        f16x8 b0v = *(const f16x8*)(b0);
        f16x8 b1v = *(const f16x8*)(b0 + 32);
        f16x8 b2v = *(const f16x8*)(b0 + 64);
        float w0 = Wskip[c0], w1s = Wskip[D1 + c0], bsv = bskip[c0];
        #pragma unroll
        for (int rt = 0; rt < 2; ++rt) {
            const _Float16* ar = As + (rt * 16 + mm) * AP1 + quad * 8;
            f32x4 acc = {0.f, 0.f, 0.f, 0.f};
            acc = __builtin_amdgcn_mfma_f32_16x16x32_f16(*(const f16x8*)(ar),      b0v, acc, 0, 0, 0);
            acc = __builtin_amdgcn_mfma_f32_16x16x32_f16(*(const f16x8*)(ar + 32), b1v, acc, 0, 0, 0);
            acc = __builtin_amdgcn_mfma_f32_16x16x32_f16(*(const f16x8*)(ar + 64), b2v, acc, 0, 0, 0);
            #pragma unroll
            for (int r = 0; r < 4; ++r) {
                int lr = rt * 16 + quad * 4 + r, gr = row0 + lr;
                float beta = betaL[lr];
                float x0 = x[gr * 2], x1 = x[gr * 2 + 1];
                float xr = x0 * w0 + x1 * w1s + bsv;
                h1f[(size_t)gr * D1 + c0] =
                    __float2half(fmaxf(beta * xr + (1.f - beta) * acc[r], 0.f));
            }
        }
    }
}

// ---------------- conv2 linears via MFMA, LDS-staged A (32-row blocks) ------
__device__ __forceinline__ void nl2_store(int c, int gr, float v,
        float* __restrict__ q2, __half* __restrict__ k2h, __half* __restrict__ v2h,
        float* __restrict__ xr2, float* __restrict__ qe) {
    if (c < 256) {
        int m = c >> 6, d = c & 63;
        if (m == 0)      q2[(size_t)gr * 64 + d] = v;
        else if (m == 1) k2h[(size_t)gr * 64 + d] = __float2half(v);
        else if (m == 2) v2h[(size_t)gr * 64 + d] = __float2half(v);
        else             xr2[(size_t)gr * 64 + d] = v;
    } else {
        qe[(size_t)gr * 32 + (c - 256)] = v;
    }
}

__global__ __launch_bounds__(256) void nl2_mfma(
        const __half* __restrict__ h1f, const __half* __restrict__ Bt,
        const float* __restrict__ bias,
        float* __restrict__ q2, __half* __restrict__ k2h,
        __half* __restrict__ v2h, float* __restrict__ xr2,
        float* __restrict__ qe) {
    __shared__ _Float16 As[NROWS2 * APAD];
    int t = threadIdx.x;
    int row0 = blockIdx.x * NROWS2;
    const float4* gsrc = (const float4*)(h1f + (size_t)row0 * 256);
    #pragma unroll
    for (int i = 0; i < NROWS2 / 8; ++i) {
        int li = i * 256 + t;
        int r = li >> 5, c8 = li & 31;
        *(float4*)(As + r * APAD + c8 * 8) = gsrc[li];
    }
    __syncthreads();
    int wave = t >> 6, lane = t & 63, quad = lane >> 4, mm = lane & 15;
    const _Float16* Bp = (const _Float16*)Bt;
    for (int ct = wave; ct < 18; ct += 4) {
        int c0 = ct * 16 + mm;
        const _Float16* b0 = Bp + (size_t)c0 * 256 + quad * 8;
        f16x8 b[8];
        #pragma unroll
        for (int s = 0; s < 8; ++s) b[s] = *(const f16x8*)(b0 + s * 32);
        float bz = bias[c0];
        #pragma unroll
        for (int rt = 0; rt < NROWS2 / 16; ++rt) {
            const _Float16* arow = As + (rt * 16 + mm) * APAD + quad * 8;
            f16x8 a[8];
            #pragma unroll
            for (int s = 0; s < 8; ++s) a[s] = *(const f16x8*)(arow + s * 32);
            f32x4 accA = {bz, bz, bz, bz};
            f32x4 accB = {0.f, 0.f, 0.f, 0.f};
            #pragma unroll
            for (int s = 0; s < 4; ++s) {
                accA = __builtin_amdgcn_mfma_f32_16x16x32_f16(a[s],     b[s],     accA, 0, 0, 0);
                accB = __builtin_amdgcn_mfma_f32_16x16x32_f16(a[s + 4], b[s + 4], accB, 0, 0, 0);
            }
            #pragma unroll
            for (int r = 0; r < 4; ++r) {
                int gr = row0 + rt * 16 + quad * 4 + r;
                nl2_store(c0, gr, accA[r] + accB[r], q2, k2h, v2h, xr2, qe);
            }
        }
    }
}

// ---------------- conv2: wave-per-edge logits, 4-edge unroll ----------------
// Latency-bound (R11: traffic -24% -> time -0%). 4 independent gather chains
// per iteration + 4 interleaved shfl trees double the per-wave MLP/ILP.
#define LG2_BLOCKS 2048
#define LG2_WAVES (LG2_BLOCKS * 4)
__global__ void logits2(const float* __restrict__ ea_s, const float* __restrict__ q2,
                        const __half* __restrict__ k2h, const float* __restrict__ qe,
                        float* __restrict__ alpha2) {
    int t = threadIdx.x, wid = t >> 6, lane = t & 63;
    int w = blockIdx.x * 4 + wid;
    for (int base = w; base < N_EDGES; base += 4 * LG2_WAVES) {
        float dd[4];
        #pragma unroll
        for (int j = 0; j < 4; ++j) {
            int p = base + j * LG2_WAVES;
            int pc = (p < N_EDGES) ? p : base;
            const float* row = ea_s + (size_t)pc * EPAD;
            int s = __float_as_int(row[20]), d = __float_as_int(row[21]);
            float acc = q2[(size_t)d * 64 + lane] * __half2float(k2h[(size_t)s * 64 + lane]);
            if (lane < 20) acc += qe[(size_t)d * 32 + lane] * row[lane];
            dd[j] = acc;                          // qe[d][18..19]==0 -> exact
        }
        #pragma unroll
        for (int off = 32; off; off >>= 1) {
            #pragma unroll
            for (int j = 0; j < 4; ++j) dd[j] += __shfl_xor(dd[j], off);
        }
        if (lane == 0) {
            #pragma unroll
            for (int j = 0; j < 4; ++j) {
                int p = base + j * LG2_WAVES;
                if (p < N_EDGES) alpha2[p] = __expf(dd[j] * 0.125f);
            }
        }
    }
}

// ---------------- conv2: 16-edge strip, preloaded: out2+=w*v, acc2+=w*[ea,1]-
__global__ void spmm2s(const float* __restrict__ ea_s,
                       const float* __restrict__ alpha2, const __half* __restrict__ v2h,
                       float* __restrict__ out2, float* __restrict__ acc2) {
    int t = threadIdx.x;
    int strip = blockIdx.x * 4 + (t >> 6);
    int lane = t & 63;
    int p0 = strip * 16;
    int dsts[16]; int srcs[16]; float w[16];
    #pragma unroll
    for (int j = 0; j < 16; ++j)
        dsts[j] = __float_as_int(ea_s[(size_t)(p0 + j) * EPAD + 21]);
    #pragma unroll
    for (int j = 0; j < 16; ++j)
        srcs[j] = __float_as_int(ea_s[(size_t)(p0 + j) * EPAD + 20]);
    #pragma unroll
    for (int j = 0; j < 16; ++j) w[j] = alpha2[p0 + j];
    float vv[16]; float ev[16];
    #pragma unroll
    for (int j = 0; j < 16; ++j) vv[j] = __half2float(v2h[(size_t)srcs[j] * 64 + lane]);
    #pragma unroll
    for (int j = 0; j < 16; ++j)
        ev[j] = (lane < EDIM) ? ea_s[(size_t)(p0 + j) * EPAD + lane] : 1.f;
    float acc = 0.f, accS = 0.f;
    int prev = dsts[0];
    #pragma unroll
    for (int j = 0; j < 16; ++j) {
        if (dsts[j] != prev) {
            atomicAdd(&out2[(size_t)prev * 64 + lane], acc);
            if (lane < 19) atomicAdd(&acc2[(size_t)prev * 20 + lane], accS);
            acc = 0.f; accS = 0.f; prev = dsts[j];
        }
        acc += w[j] * vv[j];
        accS += w[j] * ev[j];
    }
    atomicAdd(&out2[(size_t)prev * 64 + lane], acc);
    if (lane < 19) atomicAdd(&acc2[(size_t)prev * 20 + lane], accS);
}

// ---------------- conv2 finalize: + e-term, normalize, beta, relu -> h2 -----
__global__ void finalize2x(const float* __restrict__ out2, const float* __restrict__ acc2,
                           const float* __restrict__ xr2, const float* __restrict__ We2,
                           const float* __restrict__ Wb2, float* __restrict__ h2) {
    __shared__ float w2s[EDIM * 64];
    int t = threadIdx.x;
    for (int i = t; i < EDIM * 64; i += 256) w2s[i] = We2[i];
    __syncthreads();
    int node = blockIdx.x * 4 + (t >> 6);
    int lane = t & 63;
    const float* a2 = acc2 + (size_t)node * 20;
    float num = out2[(size_t)node * 64 + lane];
    #pragma unroll
    for (int j = 0; j < EDIM; ++j) num += a2[j] * w2s[j * 64 + lane];
    float o = num / (a2[18] + 1e-16f);
    float xr = xr2[(size_t)node * 64 + lane];
    float part = o * Wb2[lane] + xr * Wb2[64 + lane] + (o - xr) * Wb2[128 + lane];
    #pragma unroll
    for (int off = 32; off; off >>= 1) part += __shfl_xor(part, off);
    float beta = 1.f / (1.f + __expf(-part));
    h2[(size_t)node * 64 + lane] = fmaxf(beta * xr + (1.f - beta) * o, 0.f);
}

// ---------------- pool: 4 blocks per graph, dense reads ----------------
__global__ void pool_kernel(const float* __restrict__ h2, const int* __restrict__ gs,
                            const int* __restrict__ ge, float* __restrict__ pooled) {
    __shared__ float red[4][64];
    int g = blockIdx.x >> 2, q = blockIdx.x & 3;
    int t = threadIdx.x, wv = t >> 6, lane = t & 63;
    int s = gs[g], e = ge[g];
    float sum = 0.f;
    for (int n = s + q * 4 + wv; n < e; n += 16) sum += h2[(size_t)n * 64 + lane];
    red[wv][lane] = sum;
    __syncthreads();
    if (wv == 0) {
        float v = red[0][lane] + red[1][lane] + red[2][lane] + red[3][lane];
        atomicAdd(&pooled[g * 64 + lane], v);
    }
}

// ---------------- final linear (cnt from graph bounds) ----------------
__global__ void final_lin(const float* __restrict__ pooled, const int* __restrict__ gs,
                          const int* __restrict__ ge,
                          const float* __restrict__ Wlin, const float* __restrict__ blin,
                          float* __restrict__ out) {
    int t = threadIdx.x;
    if (t >= N_GRAPHS * OUTF) return;
    int g = t / OUTF, o = t % OUTF;
    int c = ge[g] - gs[g];
    float inv = 1.f / fmaxf((float)c, 1.f);
    float acc = 0.f;
    for (int kk = 0; kk < HIDC; ++kk) acc += pooled[g * 64 + kk] * Wlin[kk * OUTF + o];
    out[t] = acc * inv + blin[o];
}

extern "C" void kernel_launch(void* const* d_in, const int* in_sizes, int n_in,
                              void* d_out, int out_size, void* d_ws, size_t ws_size,
                              hipStream_t stream) {
    const float* x      = (const float*)d_in[0];
    const int*   ei     = (const int*)d_in[1];
    const float* ea     = (const float*)d_in[2];
    const int*   batch  = (const int*)d_in[3];
    const float* Wq1    = (const float*)d_in[4];  const float* bq1    = (const float*)d_in[5];
    const float* Wk1    = (const float*)d_in[6];  const float* bk1    = (const float*)d_in[7];
    const float* Wv1    = (const float*)d_in[8];  const float* bv1    = (const float*)d_in[9];
    const float* We1    = (const float*)d_in[10];
    const float* Wskip1 = (const float*)d_in[11]; const float* bskip1 = (const float*)d_in[12];
    const float* Wbeta1 = (const float*)d_in[13];
    const float* Wq2    = (const float*)d_in[14]; const float* bq2    = (const float*)d_in[15];
    const float* Wk2    = (const float*)d_in[16]; const float* bk2    = (const float*)d_in[17];
    const float* Wv2    = (const float*)d_in[18]; const float* bv2    = (const float*)d_in[19];
    const float* We2    = (const float*)d_in[20];
    const float* Wskip2 = (const float*)d_in[21]; const float* bskip2 = (const float*)d_in[22];
    const float* Wbeta2 = (const float*)d_in[23];
    const float* Wlin   = (const float*)d_in[24]; const float* blin   = (const float*)d_in[25];

    float* ptr = (float*)d_ws;
    float* q2     = ptr; ptr += (size_t)N_NODES * 64;
    __half* k2h   = (__half*)ptr; ptr += (size_t)N_NODES * 32;   // k2 in half
    float* xr2    = ptr; ptr += (size_t)N_NODES * 64;
    float* qe     = ptr; ptr += (size_t)N_NODES * 32;
    __half* v2h   = (__half*)ptr; ptr += (size_t)N_NODES * 32;
    float* ea_s   = ptr; ptr += (size_t)N_EDGES * EPAD;   // 128B-aligned rows
    float* alpha2 = ptr; ptr += N_EDGES;
    float* acc2   = ptr; ptr += (size_t)N_NODES * 20;
    float* out2   = ptr; ptr += (size_t)N_NODES * 64;
    float* pooled = ptr; ptr += N_GRAPHS * HIDC;
    int*   gs     = (int*)ptr; ptr += N_GRAPHS;
    int*   ge     = (int*)ptr; ptr += N_GRAPHS;
    float* cbuf   = ptr; ptr += 256;
    float* bias   = ptr; ptr += 320;                 // 288 used + s0..s2 at 288..290
    __half* Bt    = (__half*)ptr; ptr += (288 * 256) / 2;
    __half* Btf   = (__half*)ptr; ptr += (272 * 96) / 2;
    __half* ah    = (__half*)ptr; ptr += (size_t)N_NODES * 48;   // N*96 halfs
    int*   deg    = (int*)ptr; ptr += N_NODES;
    int*   cursor = (int*)ptr; ptr += N_NODES;
    int*   bsum   = (int*)ptr; ptr += 256;
    int*   boff   = (int*)ptr; ptr += 256;
    float* w1     = ptr; ptr += (size_t)N_EDGES * 4;    // conv1 edge weights [E][4]
    float* h2     = ptr; ptr += (size_t)N_NODES * 64;
    float* acc1   = ptr; ptr += (size_t)N_NODES * 84;
    __half* h1f   = (__half*)ptr; ptr += (size_t)N_NODES * 128;  // N*256 halfs

    const int EB = (N_EDGES + 255) / 256;

    // ---- weights + init + CSR ----
    prep_w<<<562, 256, 0, stream>>>(Wq2, bq2, Wk2, bk2, Wv2, bv2, Wskip2, bskip2, We2,
                                    Wq1, bq1, Wk1, bk1, We1,
                                    Wv1, bv1, Wskip1, bskip1, Wbeta1,
                                    Bt, bias, cbuf, Btf);
    initA<<<(N_NODES * 84) / 256, 256, 0, stream>>>(acc1, acc2, out2, deg, pooled, gs, ge);
    hist_kernel<<<EB, 256, 0, stream>>>(ei, deg, batch, gs, ge);
    scanA<<<250, 256, 0, stream>>>(deg, bsum);
    scanB<<<1, 256, 0, stream>>>(bsum, boff);
    scanC<<<250, 256, 0, stream>>>(deg, boff, cursor);
    scatterE<<<(N_EDGES / 2 + 255) / 256, 256, 0, stream>>>(ei, ea, x, cursor, ea_s);

    // ---- conv1 ----
    logits1<<<EB, 256, 0, stream>>>(ea_s, x, cbuf, w1);
    strip1f<<<(N_EDGES / 16) / 2, 256, 0, stream>>>(ea_s, w1, acc1);
    scale1<<<(N_NODES * 96) / 256, 256, 0, stream>>>(acc1, ah);
    fin1_mfma<<<N_NODES / 32, 256, 0, stream>>>(ah, Btf, x, bias, Wskip1, bskip1, h1f);

    // ---- conv2 ----
    nl2_mfma<<<N_NODES / NROWS2, 256, 0, stream>>>(h1f, Bt, bias, q2, k2h, v2h, xr2, qe);
    logits2<<<LG2_BLOCKS, 256, 0, stream>>>(ea_s, q2, k2h, qe, alpha2);
    spmm2s<<<(N_EDGES / 16) / 4, 256, 0, stream>>>(ea_s, alpha2, v2h, out2, acc2);
    finalize2x<<<N_NODES / 4, 256, 0, stream>>>(out2, acc2, xr2, We2, Wbeta2, h2);

    // ---- pool + head ----
    pool_kernel<<<N_GRAPHS * 4, 256, 0, stream>>>(h2, gs, ge, pooled);
    final_lin<<<1, 256, 0, stream>>>(pooled, gs, ge, Wlin, blin, (float*)d_out);
}

// Round 13
// 401.694 us; speedup vs baseline: 1.0638x; 1.0638x over previous
//
#include <hip/hip_runtime.h>
#include <hip/hip_fp16.h>

#define N_NODES 40000
#define N_EDGES 400000
#define N_GRAPHS 64
#define D1 256      // heads*hid for conv1
#define HIDC 64
#define NHEADS 4
#define EDIM 18
#define EPAD 32     // staged row = one aligned 128B line, fully written by 1 thread
                    // 0..17 ea | 18,19 x[src] | 20 src | 21 dst | 22..31 zero
#define OUTF 3
#define APAD 264    // LDS row stride in halfs for nl2 (256 + 8 pad)
#define NROWS2 32   // rows per MFMA block (1250 blocks -> occupancy; R7 win)
#define AP1 104     // LDS row stride in halfs for fin1 (96 + 8 pad)

typedef _Float16 f16x8 __attribute__((ext_vector_type(8)));
typedef float f32x4 __attribute__((ext_vector_type(4)));

// ---------------- prep: pack conv2 weights + conv1 cbuf + conv1 finalize
// MFMA weights Btf (96x272 block-diag + beta column) + beta scalars ---------
__global__ void prep_w(const float* __restrict__ Wq, const float* __restrict__ bq,
                       const float* __restrict__ Wk, const float* __restrict__ bk,
                       const float* __restrict__ Wv, const float* __restrict__ bv,
                       const float* __restrict__ Ws, const float* __restrict__ bs,
                       const float* __restrict__ We2,
                       const float* __restrict__ Wq1, const float* __restrict__ bq1,
                       const float* __restrict__ Wk1, const float* __restrict__ bk1,
                       const float* __restrict__ We1,
                       const float* __restrict__ Wv1, const float* __restrict__ bv1,
                       const float* __restrict__ Ws1, const float* __restrict__ bs1,
                       const float* __restrict__ Wb1,
                       __half* __restrict__ Bt, float* __restrict__ bias,
                       float* __restrict__ cbuf, __half* __restrict__ Btf) {
    int c = blockIdx.x, k = threadIdx.x;
    if (c < 256) {
        int m = c >> 6, d = c & 63;
        const float* W = (m == 0) ? Wq : (m == 1) ? Wk : (m == 2) ? Wv : Ws;
        Bt[c * 256 + k] = __float2half(W[k * 64 + d]);
        if (k == 0) {
            const float* b = (m == 0) ? bq : (m == 1) ? bk : (m == 2) ? bv : bs;
            bias[c] = b[d];
        }
    } else if (c < 288) {
        int j = c - 256;
        float s = 0.f;
        if (j < EDIM)
            for (int cc = 0; cc < 64; ++cc) s += Wq[k * 64 + cc] * We2[j * 64 + cc];
        Bt[c * 256 + k] = __float2half(s);
        if (k == 0) {
            float b = 0.f;
            if (j < EDIM)
                for (int cc = 0; cc < 64; ++cc) b += bq[cc] * We2[j * 64 + cc];
            bias[c] = b;
        }
    } else if (c == 288) {
        int t = k;
        if (t < 36) {
            int h = t / 9, r = t % 9, a = r / 3, b = r % 3;
            const float* A = (a == 0) ? Wq1 : (a == 1) ? Wq1 + D1 : bq1;
            const float* B = (b == 0) ? Wk1 : (b == 1) ? Wk1 + D1 : bk1;
            float s = 0.f;
            for (int cc = 0; cc < 64; ++cc) s += A[h * 64 + cc] * B[h * 64 + cc];
            cbuf[h * 63 + a * 3 + b] = s;
        } else if (t < 252) {
            int i = t - 36;
            int h = i / 54, rr = (i % 54) / 18, j = i % 18;
            const float* A = (rr == 0) ? Wq1 : (rr == 1) ? Wq1 + D1 : bq1;
            float s = 0.f;
            for (int cc = 0; cc < 64; ++cc) s += A[h * 64 + cc] * We1[j * D1 + h * 64 + cc];
            cbuf[h * 63 + 9 + rr * 18 + j] = s;
        }
    } else if (c < 561) {
        // Btf[c2][k]: conv1 finalize weights, K=96 (4 heads x 24), N=272.
        int c2 = c - 289;
        if (k < 96) {
            int hk = k / 24, j = k % 24;
            float val = 0.f;
            if (c2 < 256) {
                int hh = c2 >> 6;
                if (hk == hh && j < 21) {
                    val = (j == 0) ? Wv1[c2] : (j == 1) ? Wv1[D1 + c2] :
                          (j == 2) ? bv1[c2] : We1[(j - 3) * D1 + c2];
                }
            } else if (c2 == 256) {
                if (j < 21) {
                    float s = 0.f;
                    for (int d = 0; d < 64; ++d) {
                        int col = hk * 64 + d;
                        float wr = (j == 0) ? Wv1[col] : (j == 1) ? Wv1[D1 + col] :
                                   (j == 2) ? bv1[col] : We1[(j - 3) * D1 + col];
                        s += wr * (Wb1[col] + Wb1[2 * D1 + col]);
                    }
                    val = s;
                }
            }
            Btf[c2 * 96 + k] = __float2half(val);
        }
    } else {
        // beta xr-part scalars: s0,s1,s2 -> bias[288..290]
        if (k < 3) {
            float s = 0.f;
            for (int d = 0; d < D1; ++d) {
                float u = Wb1[D1 + d] - Wb1[2 * D1 + d];
                float w = (k == 0) ? Ws1[d] : (k == 1) ? Ws1[D1 + d] : bs1[d];
                s += w * u;
            }
            bias[288 + k] = s;
        }
    }
}

// ---------------- init (zero fill, merged) ----------------
__global__ void initA(float* __restrict__ acc1, float* __restrict__ acc2,
                      float* __restrict__ out2, int* __restrict__ deg,
                      float* __restrict__ pooled,
                      int* __restrict__ gs, int* __restrict__ ge) {
    int t = blockIdx.x * 256 + threadIdx.x;      // N*84 threads exact
    acc1[t] = 0.f;
    if (t < N_NODES * 64) out2[t] = 0.f;
    if (t < N_NODES * 20) acc2[t] = 0.f;
    if (t < N_NODES) deg[t] = 0;
    if (t < N_GRAPHS * HIDC) pooled[t] = 0.f;
    if (t < N_GRAPHS) { gs[t] = 0; ge[t] = 0; }
}

// ---------------- CSR hist + graph bounds (merged) ----------------
__global__ void hist_kernel(const int* __restrict__ ei, int* __restrict__ deg,
                            const int* __restrict__ batch, int* __restrict__ gs,
                            int* __restrict__ ge) {
    int e = blockIdx.x * 256 + threadIdx.x;
    if (e < N_EDGES) atomicAdd(&deg[ei[N_EDGES + e]], 1);
    int n = e;
    if (n < N_NODES) {
        int b = batch[n];
        if (n == 0) gs[b] = 0;
        else { int pb = batch[n - 1]; if (pb != b) { ge[pb] = n; gs[b] = n; } }
        if (n == N_NODES - 1) ge[b] = N_NODES;
    }
}

// ---------------- 3-kernel coalesced scan -> cursor ----------------
__global__ void scanA(const int* __restrict__ deg, int* __restrict__ bsum) {
    __shared__ int s[256];
    int b = blockIdx.x, t = threadIdx.x;
    s[t] = (t < 160) ? deg[b * 160 + t] : 0;
    __syncthreads();
    for (int off = 128; off; off >>= 1) {
        if (t < off) s[t] += s[t + off];
        __syncthreads();
    }
    if (t == 0) bsum[b] = s[0];
}

__global__ void scanB(const int* __restrict__ bsum, int* __restrict__ boff) {
    __shared__ int s[256];
    int t = threadIdx.x;
    int v = (t < 250) ? bsum[t] : 0;
    s[t] = v;
    __syncthreads();
    for (int off = 1; off < 256; off <<= 1) {
        int add = (t >= off) ? s[t - off] : 0;
        __syncthreads();
        s[t] += add;
        __syncthreads();
    }
    if (t < 250) boff[t] = s[t] - v;             // exclusive
}

__global__ void scanC(const int* __restrict__ deg, const int* __restrict__ boff,
                      int* __restrict__ cursor) {
    __shared__ int s[256];
    int b = blockIdx.x, t = threadIdx.x;
    int v = (t < 160) ? deg[b * 160 + t] : 0;
    s[t] = v;
    __syncthreads();
    for (int off = 1; off < 256; off <<= 1) {
        int add = (t >= off) ? s[t - off] : 0;
        __syncthreads();
        s[t] += add;
        __syncthreads();
    }
    if (t < 160) cursor[b * 160 + t] = boff[b] + s[t] - v;
}

// ---------------- fused perm + scatter staging (e-order, coalesced reads) ---
// 2 edges/thread: both atomics issued up front (independent latency chains),
// rows processed sequentially to bound VGPR.
__global__ void scatterE(const int* __restrict__ ei, const float* __restrict__ ea,
                         const float* __restrict__ x, int* __restrict__ cursor,
                         float* __restrict__ ea_s) {
    const int HALF = N_EDGES / 2;
    int e0 = blockIdx.x * 256 + threadIdx.x;
    if (e0 >= HALF) return;
    int eA = e0, eB = e0 + HALF;
    int srcA = ei[eA], dstA = ei[N_EDGES + eA];
    int srcB = ei[eB], dstB = ei[N_EDGES + eB];
    int pA = atomicAdd(&cursor[dstA], 1);
    int pB = atomicAdd(&cursor[dstB], 1);
    #pragma unroll
    for (int half = 0; half < 2; ++half) {
        int e   = half ? eB : eA;
        int src = half ? srcB : srcA;
        int dst = half ? dstB : dstA;
        int p   = half ? pB : pA;
        const float2* sr = (const float2*)(ea + (size_t)e * EDIM);   // 8B aligned
        float2 s0 = sr[0], s1 = sr[1], s2 = sr[2], s3 = sr[3], s4 = sr[4],
               s5 = sr[5], s6 = sr[6], s7 = sr[7], s8 = sr[8];
        float2 xv = *(const float2*)(x + (size_t)src * 2);           // L2-hit
        float4* drow = (float4*)(ea_s + (size_t)p * EPAD);           // 128B line
        drow[0] = make_float4(s0.x, s0.y, s1.x, s1.y);
        drow[1] = make_float4(s2.x, s2.y, s3.x, s3.y);
        drow[2] = make_float4(s4.x, s4.y, s5.x, s5.y);
        drow[3] = make_float4(s6.x, s6.y, s7.x, s7.y);
        drow[4] = make_float4(s8.x, s8.y, xv.x, xv.y);
        drow[5] = make_float4(__int_as_float(src), __int_as_float(dst), 0.f, 0.f);
        drow[6] = make_float4(0.f, 0.f, 0.f, 0.f);
        drow[7] = make_float4(0.f, 0.f, 0.f, 0.f);
    }
}

// ---------------- conv1 logits, p-order (coalesced row reads) ---------------
__global__ void logits1(const float* __restrict__ ea_s, const float* __restrict__ x,
                        const float* __restrict__ cbuf, float* __restrict__ w1) {
    __shared__ float cb[252];
    int t = threadIdx.x;
    if (t < 252) cb[t] = cbuf[t];
    __syncthreads();
    int p = blockIdx.x * 256 + t;
    if (p >= N_EDGES) return;
    const float4* row = (const float4*)(ea_s + (size_t)p * EPAD);
    float4 r0 = row[0], r1 = row[1], r2 = row[2], r3 = row[3], r4 = row[4], r5 = row[5];
    float s[EDIM];
    s[0]=r0.x; s[1]=r0.y; s[2]=r0.z; s[3]=r0.w;
    s[4]=r1.x; s[5]=r1.y; s[6]=r1.z; s[7]=r1.w;
    s[8]=r2.x; s[9]=r2.y; s[10]=r2.z; s[11]=r2.w;
    s[12]=r3.x; s[13]=r3.y; s[14]=r3.z; s[15]=r3.w;
    s[16]=r4.x; s[17]=r4.y;
    float xs0 = r4.z, xs1 = r4.w;
    int dst = __float_as_int(r5.y);
    float2 xd = *(const float2*)(x + (size_t)dst * 2);           // L2-hit
    float w[NHEADS];
    #pragma unroll
    for (int h = 0; h < NHEADS; ++h) {
        const float* c = cb + h * 63;
        float alpha = 0.f;
        #pragma unroll
        for (int a = 0; a < 3; ++a) {
            float tv = c[a * 3] * xs0 + c[a * 3 + 1] * xs1 + c[a * 3 + 2];
            const float* cc = c + 9 + a * 18;
            #pragma unroll
            for (int j = 0; j < EDIM; ++j) tv += cc[j] * s[j];
            alpha += tv * ((a == 0) ? xd.x : (a == 1) ? xd.y : 1.f);
        }
        w[h] = __expf(alpha * 0.125f);
    }
    *(float4*)(w1 + (size_t)p * 4) = make_float4(w[0], w[1], w[2], w[3]);
}

// ---------------- conv1: 16-edge strip, pure segmented acc += w*v -----------
__global__ void strip1f(const float* __restrict__ ea_s, const float* __restrict__ w1,
                        float* __restrict__ acc1) {
    int t = threadIdx.x;
    int strip = blockIdx.x * 2 + (t >> 7);       // 2 strips per 256-block
    int l = t & 127;
    int h = l >> 5, comp = l & 31;
    bool active = comp < 21;
    int voff = (comp == 0) ? 18 : (comp == 1) ? 19 : (comp >= 3 ? comp - 3 : 0);
    bool isone = (comp == 2);
    int cidx = h * 21 + comp;                    // valid when active
    int p0 = strip * 16;
    int dsts[16]; float v[16]; float w[16];
    #pragma unroll
    for (int j = 0; j < 16; ++j)
        dsts[j] = __float_as_int(ea_s[(size_t)(p0 + j) * EPAD + 21]);
    #pragma unroll
    for (int j = 0; j < 16; ++j) w[j] = w1[(size_t)(p0 + j) * 4 + h];
    #pragma unroll
    for (int j = 0; j < 16; ++j)
        v[j] = active ? (isone ? 1.f : ea_s[(size_t)(p0 + j) * EPAD + voff]) : 0.f;
    float acc = 0.f;
    int prev = dsts[0];
    #pragma unroll
    for (int j = 0; j < 16; ++j) {
        if (dsts[j] != prev) {                   // wave-uniform branch
            if (active) atomicAdd(&acc1[(size_t)prev * 84 + cidx], acc);
            acc = 0.f; prev = dsts[j];
        }
        acc += w[j] * v[j];
    }
    if (active) atomicAdd(&acc1[(size_t)prev * 84 + cidx], acc);
}

// ---------------- conv1 finalize stage A: a_sc = acc1/l as half, K=96 -------
__global__ void scale1(const float* __restrict__ acc1, __half* __restrict__ ah) {
    int tg = blockIdx.x * 256 + threadIdx.x;     // N*96 threads exact
    int node = tg / 96, k = tg % 96;
    int h = k / 24, j = k % 24;
    float val = 0.f;
    if (j < 21) {
        const float* a = acc1 + (size_t)node * 84 + h * 21;
        float l = a[2];
        float inv = 1.f / (l + 1e-16f);
        val = (j == 2) ? l * inv : a[j] * inv;
    }
    ah[tg] = __float2half(val);
}

// ---------------- conv1 finalize stage B: MFMA matvec + beta + relu ---------
__global__ __launch_bounds__(256) void fin1_mfma(
        const __half* __restrict__ ah, const __half* __restrict__ Btf,
        const float* __restrict__ x, const float* __restrict__ bias,
        const float* __restrict__ Wskip, const float* __restrict__ bskip,
        __half* __restrict__ h1f) {
    __shared__ _Float16 As[32 * AP1];
    __shared__ float betaL[32];
    int t = threadIdx.x;
    int row0 = blockIdx.x * 32;
    const float4* gsrc = (const float4*)(ah + (size_t)row0 * 96);
    #pragma unroll
    for (int i = 0; i < 2; ++i) {
        int li = i * 256 + t;                    // 384 chunks of 8 halfs
        if (li < 384) {
            int r = li / 12, c8 = li % 12;
            *(float4*)(As + r * AP1 + c8 * 8) = gsrc[li];
        }
    }
    __syncthreads();
    int wave = t >> 6, lane = t & 63, quad = lane >> 4, mm = lane & 15;
    const _Float16* Bp = (const _Float16*)Btf;
    int ct0 = (wave == 0) ? 16 : wave;
    f32x4 st[2];
    {
        int c0 = ct0 * 16 + mm;
        const _Float16* b0 = Bp + (size_t)c0 * 96 + quad * 8;
        f16x8 b0v = *(const f16x8*)(b0);
        f16x8 b1v = *(const f16x8*)(b0 + 32);
        f16x8 b2v = *(const f16x8*)(b0 + 64);
        #pragma unroll
        for (int rt = 0; rt < 2; ++rt) {
            const _Float16* ar = As + (rt * 16 + mm) * AP1 + quad * 8;
            f32x4 acc = {0.f, 0.f, 0.f, 0.f};
            acc = __builtin_amdgcn_mfma_f32_16x16x32_f16(*(const f16x8*)(ar),      b0v, acc, 0, 0, 0);
            acc = __builtin_amdgcn_mfma_f32_16x16x32_f16(*(const f16x8*)(ar + 32), b1v, acc, 0, 0, 0);
            acc = __builtin_amdgcn_mfma_f32_16x16x32_f16(*(const f16x8*)(ar + 64), b2v, acc, 0, 0, 0);
            st[rt] = acc;
        }
        if (wave == 0 && mm == 0) {              // col 256 lanes -> beta partials
            #pragma unroll
            for (int rt = 0; rt < 2; ++rt)
                #pragma unroll
                for (int r = 0; r < 4; ++r)
                    betaL[rt * 16 + quad * 4 + r] = st[rt][r];
        }
    }
    __syncthreads();
    if (t < 32) {
        int nd = row0 + t;
        float x0 = x[nd * 2], x1 = x[nd * 2 + 1];
        float lg = betaL[t] + x0 * bias[288] + x1 * bias[289] + bias[290];
        betaL[t] = 1.f / (1.f + __expf(-lg));
    }
    __syncthreads();
    if (wave != 0) {
        int c0 = ct0 * 16 + mm;
        float w0 = Wskip[c0], w1s = Wskip[D1 + c0], bsv = bskip[c0];
        #pragma unroll
        for (int rt = 0; rt < 2; ++rt)
            #pragma unroll
            for (int r = 0; r < 4; ++r) {
                int lr = rt * 16 + quad * 4 + r, gr = row0 + lr;
                float beta = betaL[lr];
                float x0 = x[gr * 2], x1 = x[gr * 2 + 1];
                float xr = x0 * w0 + x1 * w1s + bsv;
                h1f[(size_t)gr * D1 + c0] =
                    __float2half(fmaxf(beta * xr + (1.f - beta) * st[rt][r], 0.f));
            }
    }
    int nit = (wave == 0) ? 5 : 4;
    for (int it = 1; it < nit; ++it) {
        int ct = (wave == 0) ? (it - 1) * 4 : wave + it * 4;
        int c0 = ct * 16 + mm;
        const _Float16* b0 = Bp + (size_t)c0 * 96 + quad * 8;
        f16x8 b0v = *(const f16x8*)(b0);
        f16x8 b1v = *(const f16x8*)(b0 + 32);
        f16x8 b2v = *(const f16x8*)(b0 + 64);
        float w0 = Wskip[c0], w1s = Wskip[D1 + c0], bsv = bskip[c0];
        #pragma unroll
        for (int rt = 0; rt < 2; ++rt) {
            const _Float16* ar = As + (rt * 16 + mm) * AP1 + quad * 8;
            f32x4 acc = {0.f, 0.f, 0.f, 0.f};
            acc = __builtin_amdgcn_mfma_f32_16x16x32_f16(*(const f16x8*)(ar),      b0v, acc, 0, 0, 0);
            acc = __builtin_amdgcn_mfma_f32_16x16x32_f16(*(const f16x8*)(ar + 32), b1v, acc, 0, 0, 0);
            acc = __builtin_amdgcn_mfma_f32_16x16x32_f16(*(const f16x8*)(ar + 64), b2v, acc, 0, 0, 0);
            #pragma unroll
            for (int r = 0; r < 4; ++r) {
                int lr = rt * 16 + quad * 4 + r, gr = row0 + lr;
                float beta = betaL[lr];
                float x0 = x[gr * 2], x1 = x[gr * 2 + 1];
                float xr = x0 * w0 + x1 * w1s + bsv;
                h1f[(size_t)gr * D1 + c0] =
                    __float2half(fmaxf(beta * xr + (1.f - beta) * acc[r], 0.f));
            }
        }
    }
}

// ---------------- conv2 linears via MFMA, LDS-staged A (32-row blocks) ------
__device__ __forceinline__ void nl2_store(int c, int gr, float v,
        float* __restrict__ q2, __half* __restrict__ k2h, __half* __restrict__ v2h,
        float* __restrict__ xr2, float* __restrict__ qe) {
    if (c < 256) {
        int m = c >> 6, d = c & 63;
        if (m == 0)      q2[(size_t)gr * 64 + d] = v;
        else if (m == 1) k2h[(size_t)gr * 64 + d] = __float2half(v);
        else if (m == 2) v2h[(size_t)gr * 64 + d] = __float2half(v);
        else             xr2[(size_t)gr * 64 + d] = v;
    } else {
        qe[(size_t)gr * 32 + (c - 256)] = v;
    }
}

__global__ __launch_bounds__(256) void nl2_mfma(
        const __half* __restrict__ h1f, const __half* __restrict__ Bt,
        const float* __restrict__ bias,
        float* __restrict__ q2, __half* __restrict__ k2h,
        __half* __restrict__ v2h, float* __restrict__ xr2,
        float* __restrict__ qe) {
    __shared__ _Float16 As[NROWS2 * APAD];
    int t = threadIdx.x;
    int row0 = blockIdx.x * NROWS2;
    const float4* gsrc = (const float4*)(h1f + (size_t)row0 * 256);
    #pragma unroll
    for (int i = 0; i < NROWS2 / 8; ++i) {
        int li = i * 256 + t;
        int r = li >> 5, c8 = li & 31;
        *(float4*)(As + r * APAD + c8 * 8) = gsrc[li];
    }
    __syncthreads();
    int wave = t >> 6, lane = t & 63, quad = lane >> 4, mm = lane & 15;
    const _Float16* Bp = (const _Float16*)Bt;
    for (int ct = wave; ct < 18; ct += 4) {
        int c0 = ct * 16 + mm;
        const _Float16* b0 = Bp + (size_t)c0 * 256 + quad * 8;
        f16x8 b[8];
        #pragma unroll
        for (int s = 0; s < 8; ++s) b[s] = *(const f16x8*)(b0 + s * 32);
        float bz = bias[c0];
        #pragma unroll
        for (int rt = 0; rt < NROWS2 / 16; ++rt) {
            const _Float16* arow = As + (rt * 16 + mm) * APAD + quad * 8;
            f16x8 a[8];
            #pragma unroll
            for (int s = 0; s < 8; ++s) a[s] = *(const f16x8*)(arow + s * 32);
            f32x4 accA = {bz, bz, bz, bz};
            f32x4 accB = {0.f, 0.f, 0.f, 0.f};
            #pragma unroll
            for (int s = 0; s < 4; ++s) {
                accA = __builtin_amdgcn_mfma_f32_16x16x32_f16(a[s],     b[s],     accA, 0, 0, 0);
                accB = __builtin_amdgcn_mfma_f32_16x16x32_f16(a[s + 4], b[s + 4], accB, 0, 0, 0);
            }
            #pragma unroll
            for (int r = 0; r < 4; ++r) {
                int gr = row0 + rt * 16 + quad * 4 + r;
                nl2_store(c0, gr, accA[r] + accB[r], q2, k2h, v2h, xr2, qe);
            }
        }
    }
}

// ---------------- conv2: wave-per-8-contiguous-edges logits -----------------
// Latency-bound: 8 independent gather chains per iteration, no clamps/selects
// (400000 % 8 == 0), all indices compile-time. Contiguous rows share L2
// prefetch; batched loads mirror spmm2s's proven pattern.
#define LG2_BLOCKS 2048
#define LG2_WAVES (LG2_BLOCKS * 4)
#define L2U 8
__global__ void logits2(const float* __restrict__ ea_s, const float* __restrict__ q2,
                        const __half* __restrict__ k2h, const float* __restrict__ qe,
                        float* __restrict__ alpha2) {
    int t = threadIdx.x, wid = t >> 6, lane = t & 63;
    int w = blockIdx.x * 4 + wid;
    for (int p0 = w * L2U; p0 < N_EDGES; p0 += LG2_WAVES * L2U) {
        int ss[L2U], dd[L2U];
        #pragma unroll
        for (int j = 0; j < L2U; ++j) {
            const float* row = ea_s + (size_t)(p0 + j) * EPAD;
            ss[j] = __float_as_int(row[20]);
            dd[j] = __float_as_int(row[21]);
        }
        float acc[L2U];
        #pragma unroll
        for (int j = 0; j < L2U; ++j)
            acc[j] = q2[(size_t)dd[j] * 64 + lane] *
                     __half2float(k2h[(size_t)ss[j] * 64 + lane]);
        if (lane < 20) {                          // qe[d][18..19]==0 -> exact
            #pragma unroll
            for (int j = 0; j < L2U; ++j)
                acc[j] += qe[(size_t)dd[j] * 32 + lane] *
                          ea_s[(size_t)(p0 + j) * EPAD + lane];
        }
        #pragma unroll
        for (int off = 32; off; off >>= 1) {
            #pragma unroll
            for (int j = 0; j < L2U; ++j) acc[j] += __shfl_xor(acc[j], off);
        }
        if (lane == 0) {
            #pragma unroll
            for (int j = 0; j < L2U; ++j)
                alpha2[p0 + j] = __expf(acc[j] * 0.125f);
        }
    }
}

// ---------------- conv2: 16-edge strip, preloaded: out2+=w*v, acc2+=w*[ea,1]-
__global__ void spmm2s(const float* __restrict__ ea_s,
                       const float* __restrict__ alpha2, const __half* __restrict__ v2h,
                       float* __restrict__ out2, float* __restrict__ acc2) {
    int t = threadIdx.x;
    int strip = blockIdx.x * 4 + (t >> 6);
    int lane = t & 63;
    int p0 = strip * 16;
    int dsts[16]; int srcs[16]; float w[16];
    #pragma unroll
    for (int j = 0; j < 16; ++j)
        dsts[j] = __float_as_int(ea_s[(size_t)(p0 + j) * EPAD + 21]);
    #pragma unroll
    for (int j = 0; j < 16; ++j)
        srcs[j] = __float_as_int(ea_s[(size_t)(p0 + j) * EPAD + 20]);
    #pragma unroll
    for (int j = 0; j < 16; ++j) w[j] = alpha2[p0 + j];
    float vv[16]; float ev[16];
    #pragma unroll
    for (int j = 0; j < 16; ++j) vv[j] = __half2float(v2h[(size_t)srcs[j] * 64 + lane]);
    #pragma unroll
    for (int j = 0; j < 16; ++j)
        ev[j] = (lane < EDIM) ? ea_s[(size_t)(p0 + j) * EPAD + lane] : 1.f;
    float acc = 0.f, accS = 0.f;
    int prev = dsts[0];
    #pragma unroll
    for (int j = 0; j < 16; ++j) {
        if (dsts[j] != prev) {
            atomicAdd(&out2[(size_t)prev * 64 + lane], acc);
            if (lane < 19) atomicAdd(&acc2[(size_t)prev * 20 + lane], accS);
            acc = 0.f; accS = 0.f; prev = dsts[j];
        }
        acc += w[j] * vv[j];
        accS += w[j] * ev[j];
    }
    atomicAdd(&out2[(size_t)prev * 64 + lane], acc);
    if (lane < 19) atomicAdd(&acc2[(size_t)prev * 20 + lane], accS);
}

// ---------------- conv2 finalize: + e-term, normalize, beta, relu -> h2 -----
__global__ void finalize2x(const float* __restrict__ out2, const float* __restrict__ acc2,
                           const float* __restrict__ xr2, const float* __restrict__ We2,
                           const float* __restrict__ Wb2, float* __restrict__ h2) {
    __shared__ float w2s[EDIM * 64];
    int t = threadIdx.x;
    for (int i = t; i < EDIM * 64; i += 256) w2s[i] = We2[i];
    __syncthreads();
    int node = blockIdx.x * 4 + (t >> 6);
    int lane = t & 63;
    const float* a2 = acc2 + (size_t)node * 20;
    float num = out2[(size_t)node * 64 + lane];
    #pragma unroll
    for (int j = 0; j < EDIM; ++j) num += a2[j] * w2s[j * 64 + lane];
    float o = num / (a2[18] + 1e-16f);
    float xr = xr2[(size_t)node * 64 + lane];
    float part = o * Wb2[lane] + xr * Wb2[64 + lane] + (o - xr) * Wb2[128 + lane];
    #pragma unroll
    for (int off = 32; off; off >>= 1) part += __shfl_xor(part, off);
    float beta = 1.f / (1.f + __expf(-part));
    h2[(size_t)node * 64 + lane] = fmaxf(beta * xr + (1.f - beta) * o, 0.f);
}

// ---------------- pool: 4 blocks per graph, dense reads ----------------
__global__ void pool_kernel(const float* __restrict__ h2, const int* __restrict__ gs,
                            const int* __restrict__ ge, float* __restrict__ pooled) {
    __shared__ float red[4][64];
    int g = blockIdx.x >> 2, q = blockIdx.x & 3;
    int t = threadIdx.x, wv = t >> 6, lane = t & 63;
    int s = gs[g], e = ge[g];
    float sum = 0.f;
    for (int n = s + q * 4 + wv; n < e; n += 16) sum += h2[(size_t)n * 64 + lane];
    red[wv][lane] = sum;
    __syncthreads();
    if (wv == 0) {
        float v = red[0][lane] + red[1][lane] + red[2][lane] + red[3][lane];
        atomicAdd(&pooled[g * 64 + lane], v);
    }
}

// ---------------- final linear (cnt from graph bounds) ----------------
__global__ void final_lin(const float* __restrict__ pooled, const int* __restrict__ gs,
                          const int* __restrict__ ge,
                          const float* __restrict__ Wlin, const float* __restrict__ blin,
                          float* __restrict__ out) {
    int t = threadIdx.x;
    if (t >= N_GRAPHS * OUTF) return;
    int g = t / OUTF, o = t % OUTF;
    int c = ge[g] - gs[g];
    float inv = 1.f / fmaxf((float)c, 1.f);
    float acc = 0.f;
    for (int kk = 0; kk < HIDC; ++kk) acc += pooled[g * 64 + kk] * Wlin[kk * OUTF + o];
    out[t] = acc * inv + blin[o];
}

extern "C" void kernel_launch(void* const* d_in, const int* in_sizes, int n_in,
                              void* d_out, int out_size, void* d_ws, size_t ws_size,
                              hipStream_t stream) {
    const float* x      = (const float*)d_in[0];
    const int*   ei     = (const int*)d_in[1];
    const float* ea     = (const float*)d_in[2];
    const int*   batch  = (const int*)d_in[3];
    const float* Wq1    = (const float*)d_in[4];  const float* bq1    = (const float*)d_in[5];
    const float* Wk1    = (const float*)d_in[6];  const float* bk1    = (const float*)d_in[7];
    const float* Wv1    = (const float*)d_in[8];  const float* bv1    = (const float*)d_in[9];
    const float* We1    = (const float*)d_in[10];
    const float* Wskip1 = (const float*)d_in[11]; const float* bskip1 = (const float*)d_in[12];
    const float* Wbeta1 = (const float*)d_in[13];
    const float* Wq2    = (const float*)d_in[14]; const float* bq2    = (const float*)d_in[15];
    const float* Wk2    = (const float*)d_in[16]; const float* bk2    = (const float*)d_in[17];
    const float* Wv2    = (const float*)d_in[18]; const float* bv2    = (const float*)d_in[19];
    const float* We2    = (const float*)d_in[20];
    const float* Wskip2 = (const float*)d_in[21]; const float* bskip2 = (const float*)d_in[22];
    const float* Wbeta2 = (const float*)d_in[23];
    const float* Wlin   = (const float*)d_in[24]; const float* blin   = (const float*)d_in[25];

    float* ptr = (float*)d_ws;
    float* q2     = ptr; ptr += (size_t)N_NODES * 64;
    __half* k2h   = (__half*)ptr; ptr += (size_t)N_NODES * 32;   // k2 in half
    float* xr2    = ptr; ptr += (size_t)N_NODES * 64;
    float* qe     = ptr; ptr += (size_t)N_NODES * 32;
    __half* v2h   = (__half*)ptr; ptr += (size_t)N_NODES * 32;
    float* ea_s   = ptr; ptr += (size_t)N_EDGES * EPAD;   // 128B-aligned rows
    float* alpha2 = ptr; ptr += N_EDGES;
    float* acc2   = ptr; ptr += (size_t)N_NODES * 20;
    float* out2   = ptr; ptr += (size_t)N_NODES * 64;
    float* pooled = ptr; ptr += N_GRAPHS * HIDC;
    int*   gs     = (int*)ptr; ptr += N_GRAPHS;
    int*   ge     = (int*)ptr; ptr += N_GRAPHS;
    float* cbuf   = ptr; ptr += 256;
    float* bias   = ptr; ptr += 320;                 // 288 used + s0..s2 at 288..290
    __half* Bt    = (__half*)ptr; ptr += (288 * 256) / 2;
    __half* Btf   = (__half*)ptr; ptr += (272 * 96) / 2;
    __half* ah    = (__half*)ptr; ptr += (size_t)N_NODES * 48;   // N*96 halfs
    int*   deg    = (int*)ptr; ptr += N_NODES;
    int*   cursor = (int*)ptr; ptr += N_NODES;
    int*   bsum   = (int*)ptr; ptr += 256;
    int*   boff   = (int*)ptr; ptr += 256;
    float* w1     = ptr; ptr += (size_t)N_EDGES * 4;    // conv1 edge weights [E][4]
    float* h2     = ptr; ptr += (size_t)N_NODES * 64;
    float* acc1   = ptr; ptr += (size_t)N_NODES * 84;
    __half* h1f   = (__half*)ptr; ptr += (size_t)N_NODES * 128;  // N*256 halfs

    const int EB = (N_EDGES + 255) / 256;

    // ---- weights + init + CSR ----
    prep_w<<<562, 256, 0, stream>>>(Wq2, bq2, Wk2, bk2, Wv2, bv2, Wskip2, bskip2, We2,
                                    Wq1, bq1, Wk1, bk1, We1,
                                    Wv1, bv1, Wskip1, bskip1, Wbeta1,
                                    Bt, bias, cbuf, Btf);
    initA<<<(N_NODES * 84) / 256, 256, 0, stream>>>(acc1, acc2, out2, deg, pooled, gs, ge);
    hist_kernel<<<EB, 256, 0, stream>>>(ei, deg, batch, gs, ge);
    scanA<<<250, 256, 0, stream>>>(deg, bsum);
    scanB<<<1, 256, 0, stream>>>(bsum, boff);
    scanC<<<250, 256, 0, stream>>>(deg, boff, cursor);
    scatterE<<<(N_EDGES / 2 + 255) / 256, 256, 0, stream>>>(ei, ea, x, cursor, ea_s);

    // ---- conv1 ----
    logits1<<<EB, 256, 0, stream>>>(ea_s, x, cbuf, w1);
    strip1f<<<(N_EDGES / 16) / 2, 256, 0, stream>>>(ea_s, w1, acc1);
    scale1<<<(N_NODES * 96) / 256, 256, 0, stream>>>(acc1, ah);
    fin1_mfma<<<N_NODES / 32, 256, 0, stream>>>(ah, Btf, x, bias, Wskip1, bskip1, h1f);

    // ---- conv2 ----
    nl2_mfma<<<N_NODES / NROWS2, 256, 0, stream>>>(h1f, Bt, bias, q2, k2h, v2h, xr2, qe);
    logits2<<<LG2_BLOCKS, 256, 0, stream>>>(ea_s, q2, k2h, qe, alpha2);
    spmm2s<<<(N_EDGES / 16) / 4, 256, 0, stream>>>(ea_s, alpha2, v2h, out2, acc2);
    finalize2x<<<N_NODES / 4, 256, 0, stream>>>(out2, acc2, xr2, We2, Wbeta2, h2);

    // ---- pool + head ----
    pool_kernel<<<N_GRAPHS * 4, 256, 0, stream>>>(h2, gs, ge, pooled);
    final_lin<<<1, 256, 0, stream>>>(pooled, gs, ge, Wlin, blin, (float*)d_out);
}

// Round 14
// 394.460 us; speedup vs baseline: 1.0834x; 1.0183x over previous
//
#include <hip/hip_runtime.h>
#include <hip/hip_fp16.h>

#define N_NODES 40000
#define N_EDGES 400000
#define N_GRAPHS 64
#define D1 256      // heads*hid for conv1
#define HIDC 64
#define NHEADS 4
#define EDIM 18
#define EPAD 32     // staged row = one aligned 128B line, fully written by 1 thread
                    // 0..17 ea | 18,19 x[src] | 20 src | 21 dst | 22..31 zero
#define OUTF 3
#define APAD 264    // LDS row stride in halfs for nl2 (256 + 8 pad)
#define NROWS2 32   // rows per MFMA block (1250 blocks -> occupancy; R7 win)
#define AP1 104     // LDS row stride in halfs for fin1 (96 + 8 pad)

typedef _Float16 f16x8 __attribute__((ext_vector_type(8)));
typedef float f32x4 __attribute__((ext_vector_type(4)));

// ---------------- prep: pack conv2 weights + conv1 cbuf + conv1 finalize
// MFMA weights Btf (96x272 block-diag + beta column) + beta scalars ---------
__global__ void prep_w(const float* __restrict__ Wq, const float* __restrict__ bq,
                       const float* __restrict__ Wk, const float* __restrict__ bk,
                       const float* __restrict__ Wv, const float* __restrict__ bv,
                       const float* __restrict__ Ws, const float* __restrict__ bs,
                       const float* __restrict__ We2,
                       const float* __restrict__ Wq1, const float* __restrict__ bq1,
                       const float* __restrict__ Wk1, const float* __restrict__ bk1,
                       const float* __restrict__ We1,
                       const float* __restrict__ Wv1, const float* __restrict__ bv1,
                       const float* __restrict__ Ws1, const float* __restrict__ bs1,
                       const float* __restrict__ Wb1,
                       __half* __restrict__ Bt, float* __restrict__ bias,
                       float* __restrict__ cbuf, __half* __restrict__ Btf) {
    int c = blockIdx.x, k = threadIdx.x;
    if (c < 256) {
        int m = c >> 6, d = c & 63;
        const float* W = (m == 0) ? Wq : (m == 1) ? Wk : (m == 2) ? Wv : Ws;
        Bt[c * 256 + k] = __float2half(W[k * 64 + d]);
        if (k == 0) {
            const float* b = (m == 0) ? bq : (m == 1) ? bk : (m == 2) ? bv : bs;
            bias[c] = b[d];
        }
    } else if (c < 288) {
        int j = c - 256;
        float s = 0.f;
        if (j < EDIM)
            for (int cc = 0; cc < 64; ++cc) s += Wq[k * 64 + cc] * We2[j * 64 + cc];
        Bt[c * 256 + k] = __float2half(s);
        if (k == 0) {
            float b = 0.f;
            if (j < EDIM)
                for (int cc = 0; cc < 64; ++cc) b += bq[cc] * We2[j * 64 + cc];
            bias[c] = b;
        }
    } else if (c == 288) {
        int t = k;
        if (t < 36) {
            int h = t / 9, r = t % 9, a = r / 3, b = r % 3;
            const float* A = (a == 0) ? Wq1 : (a == 1) ? Wq1 + D1 : bq1;
            const float* B = (b == 0) ? Wk1 : (b == 1) ? Wk1 + D1 : bk1;
            float s = 0.f;
            for (int cc = 0; cc < 64; ++cc) s += A[h * 64 + cc] * B[h * 64 + cc];
            cbuf[h * 63 + a * 3 + b] = s;
        } else if (t < 252) {
            int i = t - 36;
            int h = i / 54, rr = (i % 54) / 18, j = i % 18;
            const float* A = (rr == 0) ? Wq1 : (rr == 1) ? Wq1 + D1 : bq1;
            float s = 0.f;
            for (int cc = 0; cc < 64; ++cc) s += A[h * 64 + cc] * We1[j * D1 + h * 64 + cc];
            cbuf[h * 63 + 9 + rr * 18 + j] = s;
        }
    } else if (c < 561) {
        // Btf[c2][k]: conv1 finalize weights, K=96 (4 heads x 24), N=272.
        int c2 = c - 289;
        if (k < 96) {
            int hk = k / 24, j = k % 24;
            float val = 0.f;
            if (c2 < 256) {
                int hh = c2 >> 6;
                if (hk == hh && j < 21) {
                    val = (j == 0) ? Wv1[c2] : (j == 1) ? Wv1[D1 + c2] :
                          (j == 2) ? bv1[c2] : We1[(j - 3) * D1 + c2];
                }
            } else if (c2 == 256) {
                if (j < 21) {
                    float s = 0.f;
                    for (int d = 0; d < 64; ++d) {
                        int col = hk * 64 + d;
                        float wr = (j == 0) ? Wv1[col] : (j == 1) ? Wv1[D1 + col] :
                                   (j == 2) ? bv1[col] : We1[(j - 3) * D1 + col];
                        s += wr * (Wb1[col] + Wb1[2 * D1 + col]);
                    }
                    val = s;
                }
            }
            Btf[c2 * 96 + k] = __float2half(val);
        }
    } else {
        // beta xr-part scalars: s0,s1,s2 -> bias[288..290]
        if (k < 3) {
            float s = 0.f;
            for (int d = 0; d < D1; ++d) {
                float u = Wb1[D1 + d] - Wb1[2 * D1 + d];
                float w = (k == 0) ? Ws1[d] : (k == 1) ? Ws1[D1 + d] : bs1[d];
                s += w * u;
            }
            bias[288 + k] = s;
        }
    }
}

// ---------------- init (zero fill, merged) ----------------
__global__ void initA(float* __restrict__ acc1, float* __restrict__ acc2,
                      float* __restrict__ out2, int* __restrict__ deg,
                      float* __restrict__ pooled,
                      int* __restrict__ gs, int* __restrict__ ge) {
    int t = blockIdx.x * 256 + threadIdx.x;      // N*84 threads exact
    acc1[t] = 0.f;
    if (t < N_NODES * 64) out2[t] = 0.f;
    if (t < N_NODES * 20) acc2[t] = 0.f;
    if (t < N_NODES) deg[t] = 0;
    if (t < N_GRAPHS * HIDC) pooled[t] = 0.f;
    if (t < N_GRAPHS) { gs[t] = 0; ge[t] = 0; }
}

// ---------------- CSR hist + graph bounds (merged) ----------------
__global__ void hist_kernel(const int* __restrict__ ei, int* __restrict__ deg,
                            const int* __restrict__ batch, int* __restrict__ gs,
                            int* __restrict__ ge) {
    int e = blockIdx.x * 256 + threadIdx.x;
    if (e < N_EDGES) atomicAdd(&deg[ei[N_EDGES + e]], 1);
    int n = e;
    if (n < N_NODES) {
        int b = batch[n];
        if (n == 0) gs[b] = 0;
        else { int pb = batch[n - 1]; if (pb != b) { ge[pb] = n; gs[b] = n; } }
        if (n == N_NODES - 1) ge[b] = N_NODES;
    }
}

// ---------------- 3-kernel coalesced scan -> cursor ----------------
__global__ void scanA(const int* __restrict__ deg, int* __restrict__ bsum) {
    __shared__ int s[256];
    int b = blockIdx.x, t = threadIdx.x;
    s[t] = (t < 160) ? deg[b * 160 + t] : 0;
    __syncthreads();
    for (int off = 128; off; off >>= 1) {
        if (t < off) s[t] += s[t + off];
        __syncthreads();
    }
    if (t == 0) bsum[b] = s[0];
}

__global__ void scanB(const int* __restrict__ bsum, int* __restrict__ boff) {
    __shared__ int s[256];
    int t = threadIdx.x;
    int v = (t < 250) ? bsum[t] : 0;
    s[t] = v;
    __syncthreads();
    for (int off = 1; off < 256; off <<= 1) {
        int add = (t >= off) ? s[t - off] : 0;
        __syncthreads();
        s[t] += add;
        __syncthreads();
    }
    if (t < 250) boff[t] = s[t] - v;             // exclusive
}

__global__ void scanC(const int* __restrict__ deg, const int* __restrict__ boff,
                      int* __restrict__ cursor) {
    __shared__ int s[256];
    int b = blockIdx.x, t = threadIdx.x;
    int v = (t < 160) ? deg[b * 160 + t] : 0;
    s[t] = v;
    __syncthreads();
    for (int off = 1; off < 256; off <<= 1) {
        int add = (t >= off) ? s[t - off] : 0;
        __syncthreads();
        s[t] += add;
        __syncthreads();
    }
    if (t < 160) cursor[b * 160 + t] = boff[b] + s[t] - v;
}

// ---------------- fused perm + scatter staging (e-order, coalesced reads) ---
// 2 edges/thread: both atomics issued up front (independent latency chains),
// rows processed sequentially to bound VGPR.
__global__ void scatterE(const int* __restrict__ ei, const float* __restrict__ ea,
                         const float* __restrict__ x, int* __restrict__ cursor,
                         float* __restrict__ ea_s) {
    const int HALF = N_EDGES / 2;
    int e0 = blockIdx.x * 256 + threadIdx.x;
    if (e0 >= HALF) return;
    int eA = e0, eB = e0 + HALF;
    int srcA = ei[eA], dstA = ei[N_EDGES + eA];
    int srcB = ei[eB], dstB = ei[N_EDGES + eB];
    int pA = atomicAdd(&cursor[dstA], 1);
    int pB = atomicAdd(&cursor[dstB], 1);
    #pragma unroll
    for (int half = 0; half < 2; ++half) {
        int e   = half ? eB : eA;
        int src = half ? srcB : srcA;
        int dst = half ? dstB : dstA;
        int p   = half ? pB : pA;
        const float2* sr = (const float2*)(ea + (size_t)e * EDIM);   // 8B aligned
        float2 s0 = sr[0], s1 = sr[1], s2 = sr[2], s3 = sr[3], s4 = sr[4],
               s5 = sr[5], s6 = sr[6], s7 = sr[7], s8 = sr[8];
        float2 xv = *(const float2*)(x + (size_t)src * 2);           // L2-hit
        float4* drow = (float4*)(ea_s + (size_t)p * EPAD);           // 128B line
        drow[0] = make_float4(s0.x, s0.y, s1.x, s1.y);
        drow[1] = make_float4(s2.x, s2.y, s3.x, s3.y);
        drow[2] = make_float4(s4.x, s4.y, s5.x, s5.y);
        drow[3] = make_float4(s6.x, s6.y, s7.x, s7.y);
        drow[4] = make_float4(s8.x, s8.y, xv.x, xv.y);
        drow[5] = make_float4(__int_as_float(src), __int_as_float(dst), 0.f, 0.f);
        drow[6] = make_float4(0.f, 0.f, 0.f, 0.f);
        drow[7] = make_float4(0.f, 0.f, 0.f, 0.f);
    }
}

// ---------------- conv1 logits, p-order (coalesced row reads) ---------------
__global__ void logits1(const float* __restrict__ ea_s, const float* __restrict__ x,
                        const float* __restrict__ cbuf, float* __restrict__ w1) {
    __shared__ float cb[252];
    int t = threadIdx.x;
    if (t < 252) cb[t] = cbuf[t];
    __syncthreads();
    int p = blockIdx.x * 256 + t;
    if (p >= N_EDGES) return;
    const float4* row = (const float4*)(ea_s + (size_t)p * EPAD);
    float4 r0 = row[0], r1 = row[1], r2 = row[2], r3 = row[3], r4 = row[4], r5 = row[5];
    float s[EDIM];
    s[0]=r0.x; s[1]=r0.y; s[2]=r0.z; s[3]=r0.w;
    s[4]=r1.x; s[5]=r1.y; s[6]=r1.z; s[7]=r1.w;
    s[8]=r2.x; s[9]=r2.y; s[10]=r2.z; s[11]=r2.w;
    s[12]=r3.x; s[13]=r3.y; s[14]=r3.z; s[15]=r3.w;
    s[16]=r4.x; s[17]=r4.y;
    float xs0 = r4.z, xs1 = r4.w;
    int dst = __float_as_int(r5.y);
    float2 xd = *(const float2*)(x + (size_t)dst * 2);           // L2-hit
    float w[NHEADS];
    #pragma unroll
    for (int h = 0; h < NHEADS; ++h) {
        const float* c = cb + h * 63;
        float alpha = 0.f;
        #pragma unroll
        for (int a = 0; a < 3; ++a) {
            float tv = c[a * 3] * xs0 + c[a * 3 + 1] * xs1 + c[a * 3 + 2];
            const float* cc = c + 9 + a * 18;
            #pragma unroll
            for (int j = 0; j < EDIM; ++j) tv += cc[j] * s[j];
            alpha += tv * ((a == 0) ? xd.x : (a == 1) ? xd.y : 1.f);
        }
        w[h] = __expf(alpha * 0.125f);
    }
    *(float4*)(w1 + (size_t)p * 4) = make_float4(w[0], w[1], w[2], w[3]);
}

// ---------------- conv1: 16-edge strip, pure segmented acc += w*v -----------
__global__ void strip1f(const float* __restrict__ ea_s, const float* __restrict__ w1,
                        float* __restrict__ acc1) {
    int t = threadIdx.x;
    int strip = blockIdx.x * 2 + (t >> 7);       // 2 strips per 256-block
    int l = t & 127;
    int h = l >> 5, comp = l & 31;
    bool active = comp < 21;
    int voff = (comp == 0) ? 18 : (comp == 1) ? 19 : (comp >= 3 ? comp - 3 : 0);
    bool isone = (comp == 2);
    int cidx = h * 21 + comp;                    // valid when active
    int p0 = strip * 16;
    int dsts[16]; float v[16]; float w[16];
    #pragma unroll
    for (int j = 0; j < 16; ++j)
        dsts[j] = __float_as_int(ea_s[(size_t)(p0 + j) * EPAD + 21]);
    #pragma unroll
    for (int j = 0; j < 16; ++j) w[j] = w1[(size_t)(p0 + j) * 4 + h];
    #pragma unroll
    for (int j = 0; j < 16; ++j)
        v[j] = active ? (isone ? 1.f : ea_s[(size_t)(p0 + j) * EPAD + voff]) : 0.f;
    float acc = 0.f;
    int prev = dsts[0];
    #pragma unroll
    for (int j = 0; j < 16; ++j) {
        if (dsts[j] != prev) {                   // wave-uniform branch
            if (active) atomicAdd(&acc1[(size_t)prev * 84 + cidx], acc);
            acc = 0.f; prev = dsts[j];
        }
        acc += w[j] * v[j];
    }
    if (active) atomicAdd(&acc1[(size_t)prev * 84 + cidx], acc);
}

// ---------------- conv1 finalize: fused scale + MFMA matvec + beta + relu ---
// Stages acc1 directly into LDS (divide by l inline) -- no ah round-trip.
__global__ __launch_bounds__(256) void fin1_mfma(
        const float* __restrict__ acc1, const __half* __restrict__ Btf,
        const float* __restrict__ x, const float* __restrict__ bias,
        const float* __restrict__ Wskip, const float* __restrict__ bskip,
        __half* __restrict__ h1f) {
    __shared__ _Float16 As[32 * AP1];
    __shared__ float betaL[32];
    __shared__ float linv[32 * 4];
    int t = threadIdx.x;
    int row0 = blockIdx.x * 32;
    if (t < 128) {                               // 1/(l+eps) per (node,head)
        int r = t >> 2, h = t & 3;
        float l = acc1[(size_t)(row0 + r) * 84 + h * 21 + 2];
        linv[t] = 1.f / (l + 1e-16f);
    }
    __syncthreads();
    #pragma unroll
    for (int i = 0; i < 12; ++i) {               // 32 rows x 96 halfs = 3072
        int idx = i * 256 + t;
        int r = idx / 96, k = idx % 96;
        int h = k / 24, j = k % 24;
        float v = 0.f;
        if (j < 21)
            v = acc1[(size_t)(row0 + r) * 84 + h * 21 + j] * linv[r * 4 + h];
        As[r * AP1 + k] = (_Float16)v;
    }
    __syncthreads();
    int wave = t >> 6, lane = t & 63, quad = lane >> 4, mm = lane & 15;
    const _Float16* Bp = (const _Float16*)Btf;
    int ct0 = (wave == 0) ? 16 : wave;
    f32x4 st[2];
    {
        int c0 = ct0 * 16 + mm;
        const _Float16* b0 = Bp + (size_t)c0 * 96 + quad * 8;
        f16x8 b0v = *(const f16x8*)(b0);
        f16x8 b1v = *(const f16x8*)(b0 + 32);
        f16x8 b2v = *(const f16x8*)(b0 + 64);
        #pragma unroll
        for (int rt = 0; rt < 2; ++rt) {
            const _Float16* ar = As + (rt * 16 + mm) * AP1 + quad * 8;
            f32x4 acc = {0.f, 0.f, 0.f, 0.f};
            acc = __builtin_amdgcn_mfma_f32_16x16x32_f16(*(const f16x8*)(ar),      b0v, acc, 0, 0, 0);
            acc = __builtin_amdgcn_mfma_f32_16x16x32_f16(*(const f16x8*)(ar + 32), b1v, acc, 0, 0, 0);
            acc = __builtin_amdgcn_mfma_f32_16x16x32_f16(*(const f16x8*)(ar + 64), b2v, acc, 0, 0, 0);
            st[rt] = acc;
        }
        if (wave == 0 && mm == 0) {              // col 256 lanes -> beta partials
            #pragma unroll
            for (int rt = 0; rt < 2; ++rt)
                #pragma unroll
                for (int r = 0; r < 4; ++r)
                    betaL[rt * 16 + quad * 4 + r] = st[rt][r];
        }
    }
    __syncthreads();
    if (t < 32) {
        int nd = row0 + t;
        float x0 = x[nd * 2], x1 = x[nd * 2 + 1];
        float lg = betaL[t] + x0 * bias[288] + x1 * bias[289] + bias[290];
        betaL[t] = 1.f / (1.f + __expf(-lg));
    }
    __syncthreads();
    if (wave != 0) {
        int c0 = ct0 * 16 + mm;
        float w0 = Wskip[c0], w1s = Wskip[D1 + c0], bsv = bskip[c0];
        #pragma unroll
        for (int rt = 0; rt < 2; ++rt)
            #pragma unroll
            for (int r = 0; r < 4; ++r) {
                int lr = rt * 16 + quad * 4 + r, gr = row0 + lr;
                float beta = betaL[lr];
                float x0 = x[gr * 2], x1 = x[gr * 2 + 1];
                float xr = x0 * w0 + x1 * w1s + bsv;
                h1f[(size_t)gr * D1 + c0] =
                    __float2half(fmaxf(beta * xr + (1.f - beta) * st[rt][r], 0.f));
            }
    }
    int nit = (wave == 0) ? 5 : 4;
    for (int it = 1; it < nit; ++it) {
        int ct = (wave == 0) ? (it - 1) * 4 : wave + it * 4;
        int c0 = ct * 16 + mm;
        const _Float16* b0 = Bp + (size_t)c0 * 96 + quad * 8;
        f16x8 b0v = *(const f16x8*)(b0);
        f16x8 b1v = *(const f16x8*)(b0 + 32);
        f16x8 b2v = *(const f16x8*)(b0 + 64);
        float w0 = Wskip[c0], w1s = Wskip[D1 + c0], bsv = bskip[c0];
        #pragma unroll
        for (int rt = 0; rt < 2; ++rt) {
            const _Float16* ar = As + (rt * 16 + mm) * AP1 + quad * 8;
            f32x4 acc = {0.f, 0.f, 0.f, 0.f};
            acc = __builtin_amdgcn_mfma_f32_16x16x32_f16(*(const f16x8*)(ar),      b0v, acc, 0, 0, 0);
            acc = __builtin_amdgcn_mfma_f32_16x16x32_f16(*(const f16x8*)(ar + 32), b1v, acc, 0, 0, 0);
            acc = __builtin_amdgcn_mfma_f32_16x16x32_f16(*(const f16x8*)(ar + 64), b2v, acc, 0, 0, 0);
            #pragma unroll
            for (int r = 0; r < 4; ++r) {
                int lr = rt * 16 + quad * 4 + r, gr = row0 + lr;
                float beta = betaL[lr];
                float x0 = x[gr * 2], x1 = x[gr * 2 + 1];
                float xr = x0 * w0 + x1 * w1s + bsv;
                h1f[(size_t)gr * D1 + c0] =
                    __float2half(fmaxf(beta * xr + (1.f - beta) * acc[r], 0.f));
            }
        }
    }
}

// ---------------- conv2 linears via MFMA, LDS-staged A (32-row blocks) ------
__device__ __forceinline__ void nl2_store(int c, int gr, float v,
        float* __restrict__ q2, __half* __restrict__ k2h, __half* __restrict__ v2h,
        float* __restrict__ xr2, float* __restrict__ qe) {
    if (c < 256) {
        int m = c >> 6, d = c & 63;
        if (m == 0)      q2[(size_t)gr * 64 + d] = v;
        else if (m == 1) k2h[(size_t)gr * 64 + d] = __float2half(v);
        else if (m == 2) v2h[(size_t)gr * 64 + d] = __float2half(v);
        else             xr2[(size_t)gr * 64 + d] = v;
    } else {
        qe[(size_t)gr * 32 + (c - 256)] = v;
    }
}

__global__ __launch_bounds__(256) void nl2_mfma(
        const __half* __restrict__ h1f, const __half* __restrict__ Bt,
        const float* __restrict__ bias,
        float* __restrict__ q2, __half* __restrict__ k2h,
        __half* __restrict__ v2h, float* __restrict__ xr2,
        float* __restrict__ qe) {
    __shared__ _Float16 As[NROWS2 * APAD];
    int t = threadIdx.x;
    int row0 = blockIdx.x * NROWS2;
    const float4* gsrc = (const float4*)(h1f + (size_t)row0 * 256);
    #pragma unroll
    for (int i = 0; i < NROWS2 / 8; ++i) {
        int li = i * 256 + t;
        int r = li >> 5, c8 = li & 31;
        *(float4*)(As + r * APAD + c8 * 8) = gsrc[li];
    }
    __syncthreads();
    int wave = t >> 6, lane = t & 63, quad = lane >> 4, mm = lane & 15;
    const _Float16* Bp = (const _Float16*)Bt;
    for (int ct = wave; ct < 18; ct += 4) {
        int c0 = ct * 16 + mm;
        const _Float16* b0 = Bp + (size_t)c0 * 256 + quad * 8;
        f16x8 b[8];
        #pragma unroll
        for (int s = 0; s < 8; ++s) b[s] = *(const f16x8*)(b0 + s * 32);
        float bz = bias[c0];
        #pragma unroll
        for (int rt = 0; rt < NROWS2 / 16; ++rt) {
            const _Float16* arow = As + (rt * 16 + mm) * APAD + quad * 8;
            f16x8 a[8];
            #pragma unroll
            for (int s = 0; s < 8; ++s) a[s] = *(const f16x8*)(arow + s * 32);
            f32x4 accA = {bz, bz, bz, bz};
            f32x4 accB = {0.f, 0.f, 0.f, 0.f};
            #pragma unroll
            for (int s = 0; s < 4; ++s) {
                accA = __builtin_amdgcn_mfma_f32_16x16x32_f16(a[s],     b[s],     accA, 0, 0, 0);
                accB = __builtin_amdgcn_mfma_f32_16x16x32_f16(a[s + 4], b[s + 4], accB, 0, 0, 0);
            }
            #pragma unroll
            for (int r = 0; r < 4; ++r) {
                int gr = row0 + rt * 16 + quad * 4 + r;
                nl2_store(c0, gr, accA[r] + accB[r], q2, k2h, v2h, xr2, qe);
            }
        }
    }
}

// ---------------- conv2: wave-per-8-contiguous-edges logits -----------------
#define LG2_BLOCKS 2048
#define LG2_WAVES (LG2_BLOCKS * 4)
#define L2U 8
__global__ void logits2(const float* __restrict__ ea_s, const float* __restrict__ q2,
                        const __half* __restrict__ k2h, const float* __restrict__ qe,
                        float* __restrict__ alpha2) {
    int t = threadIdx.x, wid = t >> 6, lane = t & 63;
    int w = blockIdx.x * 4 + wid;
    for (int p0 = w * L2U; p0 < N_EDGES; p0 += LG2_WAVES * L2U) {
        int ss[L2U], dd[L2U];
        #pragma unroll
        for (int j = 0; j < L2U; ++j) {
            const float* row = ea_s + (size_t)(p0 + j) * EPAD;
            ss[j] = __float_as_int(row[20]);
            dd[j] = __float_as_int(row[21]);
        }
        float acc[L2U];
        #pragma unroll
        for (int j = 0; j < L2U; ++j)
            acc[j] = q2[(size_t)dd[j] * 64 + lane] *
                     __half2float(k2h[(size_t)ss[j] * 64 + lane]);
        if (lane < 20) {                          // qe[d][18..19]==0 -> exact
            #pragma unroll
            for (int j = 0; j < L2U; ++j)
                acc[j] += qe[(size_t)dd[j] * 32 + lane] *
                          ea_s[(size_t)(p0 + j) * EPAD + lane];
        }
        #pragma unroll
        for (int off = 32; off; off >>= 1) {
            #pragma unroll
            for (int j = 0; j < L2U; ++j) acc[j] += __shfl_xor(acc[j], off);
        }
        if (lane == 0) {
            #pragma unroll
            for (int j = 0; j < L2U; ++j)
                alpha2[p0 + j] = __expf(acc[j] * 0.125f);
        }
    }
}

// ---------------- conv2: 16-edge strip, preloaded: out2+=w*v, acc2+=w*[ea,1]-
__global__ void spmm2s(const float* __restrict__ ea_s,
                       const float* __restrict__ alpha2, const __half* __restrict__ v2h,
                       float* __restrict__ out2, float* __restrict__ acc2) {
    int t = threadIdx.x;
    int strip = blockIdx.x * 4 + (t >> 6);
    int lane = t & 63;
    int p0 = strip * 16;
    int dsts[16]; int srcs[16]; float w[16];
    #pragma unroll
    for (int j = 0; j < 16; ++j)
        dsts[j] = __float_as_int(ea_s[(size_t)(p0 + j) * EPAD + 21]);
    #pragma unroll
    for (int j = 0; j < 16; ++j)
        srcs[j] = __float_as_int(ea_s[(size_t)(p0 + j) * EPAD + 20]);
    #pragma unroll
    for (int j = 0; j < 16; ++j) w[j] = alpha2[p0 + j];
    float vv[16]; float ev[16];
    #pragma unroll
    for (int j = 0; j < 16; ++j) vv[j] = __half2float(v2h[(size_t)srcs[j] * 64 + lane]);
    #pragma unroll
    for (int j = 0; j < 16; ++j)
        ev[j] = (lane < EDIM) ? ea_s[(size_t)(p0 + j) * EPAD + lane] : 1.f;
    float acc = 0.f, accS = 0.f;
    int prev = dsts[0];
    #pragma unroll
    for (int j = 0; j < 16; ++j) {
        if (dsts[j] != prev) {
            atomicAdd(&out2[(size_t)prev * 64 + lane], acc);
            if (lane < 19) atomicAdd(&acc2[(size_t)prev * 20 + lane], accS);
            acc = 0.f; accS = 0.f; prev = dsts[j];
        }
        acc += w[j] * vv[j];
        accS += w[j] * ev[j];
    }
    atomicAdd(&out2[(size_t)prev * 64 + lane], acc);
    if (lane < 19) atomicAdd(&acc2[(size_t)prev * 20 + lane], accS);
}

// ---------------- conv2 finalize: + e-term, normalize, beta, relu -> h2 -----
__global__ void finalize2x(const float* __restrict__ out2, const float* __restrict__ acc2,
                           const float* __restrict__ xr2, const float* __restrict__ We2,
                           const float* __restrict__ Wb2, float* __restrict__ h2) {
    __shared__ float w2s[EDIM * 64];
    int t = threadIdx.x;
    for (int i = t; i < EDIM * 64; i += 256) w2s[i] = We2[i];
    __syncthreads();
    int node = blockIdx.x * 4 + (t >> 6);
    int lane = t & 63;
    const float* a2 = acc2 + (size_t)node * 20;
    float num = out2[(size_t)node * 64 + lane];
    #pragma unroll
    for (int j = 0; j < EDIM; ++j) num += a2[j] * w2s[j * 64 + lane];
    float o = num / (a2[18] + 1e-16f);
    float xr = xr2[(size_t)node * 64 + lane];
    float part = o * Wb2[lane] + xr * Wb2[64 + lane] + (o - xr) * Wb2[128 + lane];
    #pragma unroll
    for (int off = 32; off; off >>= 1) part += __shfl_xor(part, off);
    float beta = 1.f / (1.f + __expf(-part));
    h2[(size_t)node * 64 + lane] = fmaxf(beta * xr + (1.f - beta) * o, 0.f);
}

// ---------------- pool: 4 blocks per graph, dense reads ----------------
__global__ void pool_kernel(const float* __restrict__ h2, const int* __restrict__ gs,
                            const int* __restrict__ ge, float* __restrict__ pooled) {
    __shared__ float red[4][64];
    int g = blockIdx.x >> 2, q = blockIdx.x & 3;
    int t = threadIdx.x, wv = t >> 6, lane = t & 63;
    int s = gs[g], e = ge[g];
    float sum = 0.f;
    for (int n = s + q * 4 + wv; n < e; n += 16) sum += h2[(size_t)n * 64 + lane];
    red[wv][lane] = sum;
    __syncthreads();
    if (wv == 0) {
        float v = red[0][lane] + red[1][lane] + red[2][lane] + red[3][lane];
        atomicAdd(&pooled[g * 64 + lane], v);
    }
}

// ---------------- final linear (cnt from graph bounds) ----------------
__global__ void final_lin(const float* __restrict__ pooled, const int* __restrict__ gs,
                          const int* __restrict__ ge,
                          const float* __restrict__ Wlin, const float* __restrict__ blin,
                          float* __restrict__ out) {
    int t = threadIdx.x;
    if (t >= N_GRAPHS * OUTF) return;
    int g = t / OUTF, o = t % OUTF;
    int c = ge[g] - gs[g];
    float inv = 1.f / fmaxf((float)c, 1.f);
    float acc = 0.f;
    for (int kk = 0; kk < HIDC; ++kk) acc += pooled[g * 64 + kk] * Wlin[kk * OUTF + o];
    out[t] = acc * inv + blin[o];
}

extern "C" void kernel_launch(void* const* d_in, const int* in_sizes, int n_in,
                              void* d_out, int out_size, void* d_ws, size_t ws_size,
                              hipStream_t stream) {
    const float* x      = (const float*)d_in[0];
    const int*   ei     = (const int*)d_in[1];
    const float* ea     = (const float*)d_in[2];
    const int*   batch  = (const int*)d_in[3];
    const float* Wq1    = (const float*)d_in[4];  const float* bq1    = (const float*)d_in[5];
    const float* Wk1    = (const float*)d_in[6];  const float* bk1    = (const float*)d_in[7];
    const float* Wv1    = (const float*)d_in[8];  const float* bv1    = (const float*)d_in[9];
    const float* We1    = (const float*)d_in[10];
    const float* Wskip1 = (const float*)d_in[11]; const float* bskip1 = (const float*)d_in[12];
    const float* Wbeta1 = (const float*)d_in[13];
    const float* Wq2    = (const float*)d_in[14]; const float* bq2    = (const float*)d_in[15];
    const float* Wk2    = (const float*)d_in[16]; const float* bk2    = (const float*)d_in[17];
    const float* Wv2    = (const float*)d_in[18]; const float* bv2    = (const float*)d_in[19];
    const float* We2    = (const float*)d_in[20];
    const float* Wskip2 = (const float*)d_in[21]; const float* bskip2 = (const float*)d_in[22];
    const float* Wbeta2 = (const float*)d_in[23];
    const float* Wlin   = (const float*)d_in[24]; const float* blin   = (const float*)d_in[25];

    float* ptr = (float*)d_ws;
    float* q2     = ptr; ptr += (size_t)N_NODES * 64;
    __half* k2h   = (__half*)ptr; ptr += (size_t)N_NODES * 32;   // k2 in half
    float* xr2    = ptr; ptr += (size_t)N_NODES * 64;
    float* qe     = ptr; ptr += (size_t)N_NODES * 32;
    __half* v2h   = (__half*)ptr; ptr += (size_t)N_NODES * 32;
    float* ea_s   = ptr; ptr += (size_t)N_EDGES * EPAD;   // 128B-aligned rows
    float* alpha2 = ptr; ptr += N_EDGES;
    float* acc2   = ptr; ptr += (size_t)N_NODES * 20;
    float* out2   = ptr; ptr += (size_t)N_NODES * 64;
    float* pooled = ptr; ptr += N_GRAPHS * HIDC;
    int*   gs     = (int*)ptr; ptr += N_GRAPHS;
    int*   ge     = (int*)ptr; ptr += N_GRAPHS;
    float* cbuf   = ptr; ptr += 256;
    float* bias   = ptr; ptr += 320;                 // 288 used + s0..s2 at 288..290
    __half* Bt    = (__half*)ptr; ptr += (288 * 256) / 2;
    __half* Btf   = (__half*)ptr; ptr += (272 * 96) / 2;
    int*   deg    = (int*)ptr; ptr += N_NODES;
    int*   cursor = (int*)ptr; ptr += N_NODES;
    int*   bsum   = (int*)ptr; ptr += 256;
    int*   boff   = (int*)ptr; ptr += 256;
    float* w1     = ptr; ptr += (size_t)N_EDGES * 4;    // conv1 edge weights [E][4]
    float* h2     = ptr; ptr += (size_t)N_NODES * 64;
    float* acc1   = ptr; ptr += (size_t)N_NODES * 84;
    __half* h1f   = (__half*)ptr; ptr += (size_t)N_NODES * 128;  // N*256 halfs

    const int EB = (N_EDGES + 255) / 256;

    // ---- weights + init + CSR ----
    prep_w<<<562, 256, 0, stream>>>(Wq2, bq2, Wk2, bk2, Wv2, bv2, Wskip2, bskip2, We2,
                                    Wq1, bq1, Wk1, bk1, We1,
                                    Wv1, bv1, Wskip1, bskip1, Wbeta1,
                                    Bt, bias, cbuf, Btf);
    initA<<<(N_NODES * 84) / 256, 256, 0, stream>>>(acc1, acc2, out2, deg, pooled, gs, ge);
    hist_kernel<<<EB, 256, 0, stream>>>(ei, deg, batch, gs, ge);
    scanA<<<250, 256, 0, stream>>>(deg, bsum);
    scanB<<<1, 256, 0, stream>>>(bsum, boff);
    scanC<<<250, 256, 0, stream>>>(deg, boff, cursor);
    scatterE<<<(N_EDGES / 2 + 255) / 256, 256, 0, stream>>>(ei, ea, x, cursor, ea_s);

    // ---- conv1 ----
    logits1<<<EB, 256, 0, stream>>>(ea_s, x, cbuf, w1);
    strip1f<<<(N_EDGES / 16) / 2, 256, 0, stream>>>(ea_s, w1, acc1);
    fin1_mfma<<<N_NODES / 32, 256, 0, stream>>>(acc1, Btf, x, bias, Wskip1, bskip1, h1f);

    // ---- conv2 ----
    nl2_mfma<<<N_NODES / NROWS2, 256, 0, stream>>>(h1f, Bt, bias, q2, k2h, v2h, xr2, qe);
    logits2<<<LG2_BLOCKS, 256, 0, stream>>>(ea_s, q2, k2h, qe, alpha2);
    spmm2s<<<(N_EDGES / 16) / 4, 256, 0, stream>>>(ea_s, alpha2, v2h, out2, acc2);
    finalize2x<<<N_NODES / 4, 256, 0, stream>>>(out2, acc2, xr2, We2, Wbeta2, h2);

    // ---- pool + head ----
    pool_kernel<<<N_GRAPHS * 4, 256, 0, stream>>>(h2, gs, ge, pooled);
    final_lin<<<1, 256, 0, stream>>>(pooled, gs, ge, Wlin, blin, (float*)d_out);
}